// Round 21
// baseline (441.494 us; speedup 1.0000x reference)
//
#include <hip/hip_runtime.h>
#include <hip/hip_bf16.h>

#define EPSV 1e-5f

using s8v = __attribute__((ext_vector_type(8))) short;
using f4v = __attribute__((ext_vector_type(4))) float;

__device__ __forceinline__ float bf2f(ushort u){
  union { unsigned int i; float f; } x; x.i = ((unsigned int)u)<<16; return x.f;
}
__device__ __forceinline__ ushort f2bf(float f){
  union { float f; unsigned int i; } x; x.f = f;
  unsigned int r = x.i + 0x7FFFu + ((x.i>>16)&1u);
  return (ushort)(r>>16);
}
__device__ __forceinline__ float wsum(float s){
  #pragma unroll
  for (int m=1;m<64;m<<=1) s += __shfl_xor(s, m);
  return s;
}
__device__ __forceinline__ float gelu_f(float t){
  return 0.5f*t*(1.0f + erff(t*0.70710678118654752f));
}

__device__ __forceinline__ void gload16(const void* g, void* l){
  __builtin_amdgcn_global_load_lds((__attribute__((address_space(1))) void*)g,
                                   (__attribute__((address_space(3))) void*)l, 16, 0, 0);
}

// ---------------- input repack: NCHW f32 (x1|x2) -> padded NHWC bf16 [8][66][66][256] ----------------
__global__ __launch_bounds__(256) void repack_in_k(const float* __restrict__ x1,
                                                   const float* __restrict__ x2,
                                                   ushort* __restrict__ Xin){
  __shared__ ushort tile[256][66];
  const int y = blockIdx.x, b = blockIdx.y, tid = threadIdx.x;
  const int xl = tid & 63, cq = tid >> 6;
  for (int it=0; it<64; it++){
    int ci = it*4 + cq;
    float v;
    if (ci < 128) v = x1[(((long)b*128 + ci)*64 + y)*64 + xl];
    else          v = x2[(((long)b*128 + (ci-128))*64 + y)*64 + xl];
    tile[ci][xl] = f2bf(v);
  }
  __syncthreads();
  for (int x=0; x<64; x++){
    Xin[(((long)b*66 + (y+1))*66 + (x+1))*256 + tid] = tile[tid][x];
  }
}

// ---------------- unified weight prep: all repacks + BN fold in ONE launch ----------------
__global__ void prep_k(const float* __restrict__ conv_w, const float* __restrict__ qkv_w,
                       const float* __restrict__ proj_w, const float* __restrict__ fc1_w,
                       const float* __restrict__ fc2_w, const float* __restrict__ conv_b,
                       const float* __restrict__ bn_g, const float* __restrict__ bn_b,
                       const float* __restrict__ bn_m, const float* __restrict__ bn_v,
                       ushort* __restrict__ Wc, ushort* __restrict__ Wq, ushort* __restrict__ Wp,
                       ushort* __restrict__ W1, ushort* __restrict__ W2,
                       float* __restrict__ scv, float* __restrict__ shv)
{
  const long total = 589824L + 393216 + 131072 + 524288 + 524288 + 256;
  for (long idx = (long)blockIdx.x*256 + threadIdx.x; idx < total; idx += (long)gridDim.x*256){
    long e = idx;
    if (e < 589824){
      int co = (int)(e / 2304), kk = (int)(e % 2304);
      int dd = kk >> 8, ci = kk & 255;
      Wc[e] = f2bf(conv_w[((long)(co*256 + ci))*9 + dd]);
      continue;
    }
    e -= 589824;
    if (e < 393216){
      int l = (int)(e / 196608), r = (int)(e % 196608);
      int k = r / 768, n = r % 768;
      Wq[(long)l*196608 + (long)n*256 + k] = f2bf(qkv_w[(long)l*196608 + r]);
      continue;
    }
    e -= 393216;
    if (e < 131072){
      int l = (int)(e / 65536), r = (int)(e % 65536);
      int k = r >> 8, n = r & 255;
      Wp[(long)l*65536 + n*256 + k] = f2bf(proj_w[(long)l*65536 + r]);
      continue;
    }
    e -= 131072;
    if (e < 524288){
      int l = (int)(e / 262144), r = (int)(e % 262144);
      int k = r >> 10, n = r & 1023;
      W1[(long)l*262144 + (long)n*256 + k] = f2bf(fc1_w[(long)l*262144 + r]);
      continue;
    }
    e -= 524288;
    if (e < 524288){
      int l = (int)(e / 262144), r = (int)(e % 262144);
      int k = r >> 8, n = r & 255;
      W2[(long)l*262144 + (long)n*1024 + k] = f2bf(fc2_w[(long)l*262144 + r]);
      continue;
    }
    e -= 524288;
    {
      int n = (int)e;
      float s = bn_g[n] * rsqrtf(bn_v[n] + EPSV);
      scv[n] = s;
      shv[n] = (conv_b[n] - bn_m[n])*s + bn_b[n];
    }
  }
}

// ================= conv GEMM (K=2304): BM=64, BN=256, BK=32 DOUBLE-buffered (40KB) =================
// fused: t=LN0(v*sc+sh) -> T ; Xb = LN_{g2,b2}(t). 2-pass 32KB CT epilogue.
__global__ __launch_bounds__(256) void gemm_conv(
    const ushort* __restrict__ Xin, const ushort* __restrict__ Wt,
    const float* __restrict__ sc, const float* __restrict__ sh,
    float* __restrict__ T, const float* __restrict__ g1, const float* __restrict__ b1,
    const float* __restrict__ g2, const float* __restrict__ b2,
    ushort* __restrict__ Xb)
{
  const int K = 2304;
  __shared__ ushort SMEM[20480];   // 40KB: 2 x (As 2048 + Bs 8192) ; CT 32KB aliases
  const int tid = threadIdx.x, wid = tid>>6, lane = tid&63;
  const int m0 = blockIdx.x*64;
  const int l15 = lane&15, lg = lane>>4;
  const int rowS = wid*16 + (lane>>2);
  const int cSrc = (((lane&3) ^ ((lane>>3)&3))*8);

  const ushort* pA;
  {
    int t = m0 + rowS;
    int b = t>>12, y = (t>>6)&63, x = t&63;
    pA = Xin + ((long)((b*66 + y+1)*66) + (x+1))*256 + cSrc;
  }
  const ushort* pB[4];
  #pragma unroll
  for (int j=0;j<4;j++) pB[j] = Wt + (long)(j*64 + rowS)*K + cSrc;

  auto stage = [&](int buf, int k0){
    ushort* S = SMEM + buf*10240;
    int dd = k0 >> 8;
    int dy = dd/3, dx = dd - dy*3;
    int koffA = ((dy-1)*66 + (dx-1))*256 + (k0 & 255);
    gload16(pA + koffA, (void*)&S[tid*8]);
    #pragma unroll
    for (int j=0;j<4;j++)
      gload16(pB[j] + k0, (void*)&S[2048 + j*2048 + tid*8]);
  };

  f4v acc[4][4] = {};

  int cur = 0;
  stage(0, 0);
  __syncthreads();
  for (int k0=0; k0<K; k0+=32){
    if (k0 + 32 < K) stage(cur^1, k0 + 32);
    const ushort* As_ = SMEM + cur*10240;
    const ushort* Bs_ = As_ + 2048;
    const int kch = (lg ^ ((l15>>1)&3))*8;
    s8v a[4], b[4];
    #pragma unroll
    for (int mi=0;mi<4;mi++) a[mi] = *(const s8v*)&As_[(mi*16 + l15)*32 + kch];
    #pragma unroll
    for (int ni=0;ni<4;ni++) b[ni] = *(const s8v*)&Bs_[(wid*64 + ni*16 + l15)*32 + kch];
    #pragma unroll
    for (int mi=0;mi<4;mi++)
      #pragma unroll
      for (int ni=0;ni<4;ni++)
        acc[mi][ni] = __builtin_amdgcn_mfma_f32_16x16x32_bf16(a[mi], b[ni], acc[mi][ni], 0,0,0);
    __syncthreads();
    cur ^= 1;
  }

  // ---- 2-pass epilogue through 32KB CT ----
  float* CT = (float*)SMEM;
  const int c0 = lane*4;
  const float4 scv4 = *(const float4*)&sc[c0], shv4 = *(const float4*)&sh[c0];
  const float4 g1v = *(const float4*)&g1[c0], b1v = *(const float4*)&b1[c0];
  const float4 g2v = *(const float4*)&g2[c0], b2v = *(const float4*)&b2[c0];

  #pragma unroll
  for (int p=0; p<2; p++){
    #pragma unroll
    for (int mi=2*p; mi<2*p+2; mi++)
      #pragma unroll
      for (int ni=0;ni<4;ni++)
        #pragma unroll
        for (int r=0;r<4;r++)
          CT[((mi-2*p)*16 + lg*4 + r)*256 + wid*64 + ni*16 + l15] = acc[mi][ni][r];
    __syncthreads();
    for (int t=0; t<8; t++){
      const int r = wid*8 + t;
      const long gmr = m0 + p*32 + r;
      float4 v = *(float4*)&CT[r*256 + c0];
      float4 t4;
      t4.x = v.x*scv4.x + shv4.x; t4.y = v.y*scv4.y + shv4.y;
      t4.z = v.z*scv4.z + shv4.z; t4.w = v.w*scv4.w + shv4.w;
      float mu = wsum(t4.x+t4.y+t4.z+t4.w) * (1.0f/256.0f);
      float d0=t4.x-mu, d1=t4.y-mu, d2=t4.z-mu, d3=t4.w-mu;
      float rs = rsqrtf(wsum(d0*d0+d1*d1+d2*d2+d3*d3)*(1.0f/256.0f) + EPSV);
      float u0 = d0*rs*g1v.x + b1v.x, u1 = d1*rs*g1v.y + b1v.y;
      float u2 = d2*rs*g1v.z + b1v.z, u3 = d3*rs*g1v.w + b1v.w;
      float4 u = {u0,u1,u2,u3};
      *(float4*)&T[gmr*256 + c0] = u;
      float mu2 = wsum(u0+u1+u2+u3) * (1.0f/256.0f);
      float e0=u0-mu2, e1=u1-mu2, e2=u2-mu2, e3=u3-mu2;
      float rs2 = rsqrtf(wsum(e0*e0+e1*e1+e2*e2+e3*e3)*(1.0f/256.0f) + EPSV);
      ushort4 o; o.x=f2bf(e0*rs2*g2v.x + b2v.x); o.y=f2bf(e1*rs2*g2v.y + b2v.y);
      o.z=f2bf(e2*rs2*g2v.z + b2v.z); o.w=f2bf(e3*rs2*g2v.w + b2v.w);
      *(ushort4*)&Xb[gmr*256 + c0] = o;
    }
    __syncthreads();
  }
}

// ================= residual GEMM: BM=64, BN=256, BK=32 DOUBLE-buffered (40KB), 2-pass epilogue ====
template<int EPI>
__global__ __launch_bounds__(256) void gemm_res(
    const ushort* __restrict__ A, const ushort* __restrict__ Wt, const float* __restrict__ bias,
    float* __restrict__ T, const float* __restrict__ g1, const float* __restrict__ b1,
    ushort* __restrict__ Xb, float* __restrict__ dout, int K)
{
  __shared__ ushort SMEM[20480];
  const int tid = threadIdx.x, wid = tid>>6, lane = tid&63;
  const int m0 = blockIdx.x*64;
  const int l15 = lane&15, lg = lane>>4;
  const int rowS = wid*16 + (lane>>2);
  const int cSrc = (((lane&3) ^ ((lane>>3)&3))*8);

  const ushort* pA = A + (long)(m0 + rowS)*K + cSrc;
  const ushort* pB[4];
  #pragma unroll
  for (int j=0;j<4;j++) pB[j] = Wt + (long)(j*64 + rowS)*K + cSrc;

  auto stage = [&](int buf, int k0){
    ushort* S = SMEM + buf*10240;
    gload16(pA + k0, (void*)&S[tid*8]);
    #pragma unroll
    for (int j=0;j<4;j++)
      gload16(pB[j] + k0, (void*)&S[2048 + j*2048 + tid*8]);
  };

  f4v acc[4][4] = {};

  int cur = 0;
  stage(0, 0);
  __syncthreads();
  for (int k0=0; k0<K; k0+=32){
    if (k0 + 32 < K) stage(cur^1, k0 + 32);
    const ushort* As_ = SMEM + cur*10240;
    const ushort* Bs_ = As_ + 2048;
    const int kch = (lg ^ ((l15>>1)&3))*8;
    s8v a[4], b[4];
    #pragma unroll
    for (int mi=0;mi<4;mi++) a[mi] = *(const s8v*)&As_[(mi*16 + l15)*32 + kch];
    #pragma unroll
    for (int ni=0;ni<4;ni++) b[ni] = *(const s8v*)&Bs_[(wid*64 + ni*16 + l15)*32 + kch];
    #pragma unroll
    for (int mi=0;mi<4;mi++)
      #pragma unroll
      for (int ni=0;ni<4;ni++)
        acc[mi][ni] = __builtin_amdgcn_mfma_f32_16x16x32_bf16(a[mi], b[ni], acc[mi][ni], 0,0,0);
    __syncthreads();
    cur ^= 1;
  }

  float* CT = (float*)SMEM;
  const int c0 = lane*4;
  const float4 bias4 = *(const float4*)&bias[c0];
  float4 g1v, b1v;
  if (EPI==1){ g1v = *(const float4*)&g1[c0]; b1v = *(const float4*)&b1[c0]; }
  const int b_ = m0>>12, y_ = (m0>>6)&63;

  #pragma unroll
  for (int p=0; p<2; p++){
    #pragma unroll
    for (int mi=2*p; mi<2*p+2; mi++)
      #pragma unroll
      for (int ni=0;ni<4;ni++)
        #pragma unroll
        for (int r=0;r<4;r++)
          CT[((mi-2*p)*16 + lg*4 + r)*256 + wid*64 + ni*16 + l15] = acc[mi][ni][r];
    __syncthreads();
    for (int t=0; t<8; t++){
      const int r = wid*8 + t;
      const long gmr = m0 + p*32 + r;
      float4 v = *(float4*)&CT[r*256 + c0];
      float4 rv = *(float4*)&T[gmr*256 + c0];
      float4 t4;
      t4.x = rv.x + v.x + bias4.x; t4.y = rv.y + v.y + bias4.y;
      t4.z = rv.z + v.z + bias4.z; t4.w = rv.w + v.w + bias4.w;
      if (EPI==3){
        *(float4*)&CT[r*256 + c0] = t4;
      } else {
        *(float4*)&T[gmr*256 + c0] = t4;
        float mu = wsum(t4.x+t4.y+t4.z+t4.w) * (1.0f/256.0f);
        float d0=t4.x-mu, d1=t4.y-mu, d2=t4.z-mu, d3=t4.w-mu;
        float rs = rsqrtf(wsum(d0*d0+d1*d1+d2*d2+d3*d3)*(1.0f/256.0f) + EPSV);
        ushort4 o; o.x=f2bf(d0*rs*g1v.x + b1v.x); o.y=f2bf(d1*rs*g1v.y + b1v.y);
        o.z=f2bf(d2*rs*g1v.z + b1v.z); o.w=f2bf(d3*rs*g1v.w + b1v.w);
        *(ushort4*)&Xb[gmr*256 + c0] = o;
      }
    }
    __syncthreads();
    if (EPI==3){
      float* obase = dout + (long)b_*524288 + (long)y_*64 + p*32;
      for (int it=0; it<32; it++){
        int e = it*256 + tid;
        int c = e>>5, xl = e&31;
        obase[(long)(c>>7)*4194304 + (long)(c&127)*4096 + xl] = CT[xl*256 + c];
      }
      __syncthreads();
    }
  }
}

// ---------------- fc1 GEMM (N=1024): BM=BN=128, BK=32 DOUBLE-buffered (32KB), bias+GELU ----------------
#define BM 128
#define BN 128
__global__ __launch_bounds__(256) void gemm_fc1(
    const ushort* __restrict__ A,
    const ushort* __restrict__ Wt, const float* __restrict__ bias,
    ushort* __restrict__ outb, int N, int K)
{
  __shared__ ushort SMEM[16384];
  const int tid = threadIdx.x, wid = tid>>6, lane = tid&63;
  const int m0 = blockIdx.x*BM, n0 = blockIdx.y*BN;
  const int wm = (wid>>1)*64, wn = (wid&1)*64;
  const int l15 = lane&15, lg = lane>>4;
  const int rowS = wid*16 + (lane>>2);
  const int cSrc = (((lane&3) ^ ((lane>>3)&3))*8);

  const ushort* pA[2];
  #pragma unroll
  for (int j=0;j<2;j++) pA[j] = A + (long)(m0 + j*64 + rowS)*K + cSrc;
  const ushort* pB[2];
  #pragma unroll
  for (int j=0;j<2;j++) pB[j] = Wt + (long)(n0 + j*64 + rowS)*K + cSrc;

  auto stage = [&](int buf, int k0){
    ushort* S = SMEM + buf*8192;
    #pragma unroll
    for (int j=0;j<2;j++)
      gload16(pA[j] + k0, (void*)&S[j*2048 + tid*8]);
    #pragma unroll
    for (int j=0;j<2;j++)
      gload16(pB[j] + k0, (void*)&S[4096 + j*2048 + tid*8]);
  };

  f4v acc[4][4] = {};

  int cur = 0;
  stage(0, 0);
  __syncthreads();
  for (int k0=0; k0<K; k0+=32){
    if (k0 + 32 < K) stage(cur^1, k0 + 32);
    const ushort* As_ = SMEM + cur*8192;
    const ushort* Bs_ = As_ + 4096;
    const int kch = (lg ^ ((l15>>1)&3))*8;
    s8v a[4], b[4];
    #pragma unroll
    for (int mi=0;mi<4;mi++) a[mi] = *(const s8v*)&As_[(wm + mi*16 + l15)*32 + kch];
    #pragma unroll
    for (int ni=0;ni<4;ni++) b[ni] = *(const s8v*)&Bs_[(wn + ni*16 + l15)*32 + kch];
    #pragma unroll
    for (int mi=0;mi<4;mi++)
      #pragma unroll
      for (int ni=0;ni<4;ni++)
        acc[mi][ni] = __builtin_amdgcn_mfma_f32_16x16x32_bf16(a[mi], b[ni], acc[mi][ni], 0,0,0);
    __syncthreads();
    cur ^= 1;
  }

  float* CT = (float*)SMEM;
  #pragma unroll
  for (int p=0; p<2; p++){
    if ((wid>>1) == p){
      #pragma unroll
      for (int mi=0;mi<4;mi++)
        #pragma unroll
        for (int ni=0;ni<4;ni++)
          #pragma unroll
          for (int r=0;r<4;r++)
            CT[(mi*16 + lg*4 + r)*128 + wn + ni*16 + l15] = acc[mi][ni][r];
    }
    __syncthreads();
    #pragma unroll
    for (int it=0; it<8; it++){
      int e = it*256 + tid;
      int row = e >> 5;
      int c4 = e & 31;
      float4 v = *(float4*)&CT[row*128 + c4*4];
      int gm = m0 + p*64 + row;
      int gn = n0 + c4*4;
      float4 bv = *(const float4*)&bias[gn];
      float t0 = gelu_f(v.x + bv.x), t1 = gelu_f(v.y + bv.y);
      float t2 = gelu_f(v.z + bv.z), t3 = gelu_f(v.w + bv.w);
      ushort4 u; u.x=f2bf(t0); u.y=f2bf(t1); u.z=f2bf(t2); u.w=f2bf(t3);
      *(ushort4*)&outb[(long)gm*N + gn] = u;
    }
    __syncthreads();
  }
}

// ---------------- qkv GEMM (N=768): BM=BN=128, BK=32 DOUBLE-buffered (32KB), window-store ----------------
__global__ __launch_bounds__(256) void gemm_qkv(
    const ushort* __restrict__ A,
    const ushort* __restrict__ Wt,
    ushort* __restrict__ outb, int K)
{
  __shared__ ushort SMEM[16384];
  const int tid = threadIdx.x, wid = tid>>6, lane = tid&63;
  const int m0 = blockIdx.x*BM, n0 = blockIdx.y*BN;
  const int wm = (wid>>1)*64, wn = (wid&1)*64;
  const int l15 = lane&15, lg = lane>>4;
  const int rowS = wid*16 + (lane>>2);
  const int cSrc = (((lane&3) ^ ((lane>>3)&3))*8);

  const ushort* pA[2];
  #pragma unroll
  for (int j=0;j<2;j++) pA[j] = A + (long)(m0 + j*64 + rowS)*K + cSrc;
  const ushort* pB[2];
  #pragma unroll
  for (int j=0;j<2;j++) pB[j] = Wt + (long)(n0 + j*64 + rowS)*K + cSrc;

  auto stage = [&](int buf, int k0){
    ushort* S = SMEM + buf*8192;
    #pragma unroll
    for (int j=0;j<2;j++)
      gload16(pA[j] + k0, (void*)&S[j*2048 + tid*8]);
    #pragma unroll
    for (int j=0;j<2;j++)
      gload16(pB[j] + k0, (void*)&S[4096 + j*2048 + tid*8]);
  };

  f4v acc[4][4] = {};

  int cur = 0;
  stage(0, 0);
  __syncthreads();
  for (int k0=0; k0<K; k0+=32){
    if (k0 + 32 < K) stage(cur^1, k0 + 32);
    const ushort* As_ = SMEM + cur*8192;
    const ushort* Bs_ = As_ + 4096;
    const int kch = (lg ^ ((l15>>1)&3))*8;
    s8v a[4], b[4];
    #pragma unroll
    for (int mi=0;mi<4;mi++) a[mi] = *(const s8v*)&As_[(wm + mi*16 + l15)*32 + kch];
    #pragma unroll
    for (int ni=0;ni<4;ni++) b[ni] = *(const s8v*)&Bs_[(wn + ni*16 + l15)*32 + kch];
    #pragma unroll
    for (int mi=0;mi<4;mi++)
      #pragma unroll
      for (int ni=0;ni<4;ni++)
        acc[mi][ni] = __builtin_amdgcn_mfma_f32_16x16x32_bf16(a[mi], b[ni], acc[mi][ni], 0,0,0);
    __syncthreads();
    cur ^= 1;
  }

  ushort* CB = SMEM;
  #pragma unroll
  for (int ni=0;ni<4;ni++){
    const int c = wn + ni*16 + l15;
    const int j = c>>3, ce = c&7;
    #pragma unroll
    for (int mi=0;mi<4;mi++)
      #pragma unroll
      for (int r=0;r<4;r++){
        const int row = wm + mi*16 + lg*4 + r;
        CB[row*128 + (((j ^ (row&7))<<3) | ce)] = f2bf(acc[mi][ni][r]);
      }
  }
  __syncthreads();

  const int tile = n0 >> 8;
  const int brq  = (n0 >> 7) & 1;
  const int b_   = m0 >> 12;
  const int Y0   = (m0 >> 6) & 63;
  if (brq == 0){
    #pragma unroll
    for (int it=0; it<8; it++){
      int g = it*256 + tid;
      int seg = g >> 4, q = g & 15;
      int h = seg >> 5, wv = seg & 31;
      int svi = q >> 2, c8 = q & 3;
      int gm_local = (svi>>1)*64 + wv*2 + (svi&1);
      int jc = h*4 + c8;
      uint4 v = *(uint4*)&CB[gm_local*128 + ((jc ^ (gm_local&7))<<3)];
      long rowb = ((long)(tile*2)*4 + h)*32768L + ((long)b_*32 + wv)*128 + (Y0*2 + svi);
      *(uint4*)&outb[rowb*32 + c8*8] = v;
    }
  } else {
    const int wv = Y0 >> 1;
    #pragma unroll
    for (int it=0; it<8; it++){
      int g = it*256 + tid;
      int h = g >> 9, rem = g & 511, sv = rem >> 2, c8 = rem & 3;
      int jc = h*4 + c8;
      uint4 v = *(uint4*)&CB[sv*128 + ((jc ^ (sv&7))<<3)];
      long rowb = ((long)(tile*2 + 1)*4 + h)*32768L + ((long)b_*32 + wv)*128 + sv;
      *(uint4*)&outb[rowb*32 + c8*8] = v;
    }
  }
}

// ---------------- stripe-window attention + LePE (swapped-QK^T, in-register P) ----------------
__global__ __launch_bounds__(256) void attn_k(
    const ushort* __restrict__ QKVw, ushort* __restrict__ ATT,
    const float* __restrict__ lepe_w, const float* __restrict__ lepe_b, int layer)
{
  __shared__ ushort q_lds[128][36];
  __shared__ ushort k_lds[128][36];
  __shared__ ushort vT[32][132];
  __shared__ float wl[32][9];
  __shared__ float bl[32];
  const int tid = threadIdx.x, wid = tid>>6, lane = tid&63;
  const int b = blockIdx.y;
  const int br = blockIdx.z;
  const int w = blockIdx.x>>2, h = blockIdx.x&3;
  const int choff = br*128 + h*32;
  const int l15 = lane&15, lg = lane>>4;

  const long rowbase = ((long)b*32 + w)*128;
  const ushort* qb = QKVw + (((long)(0*2+br)*4 + h)*32768L + rowbase)*32;
  const ushort* kb = QKVw + (((long)(1*2+br)*4 + h)*32768L + rowbase)*32;
  const ushort* vb = QKVw + (((long)(2*2+br)*4 + h)*32768L + rowbase)*32;

  for (int e = tid; e < 512; e += 256){
    int row = e>>2, c4 = (e&3)*8;
    *(uint4*)&q_lds[row][c4] = *(const uint4*)(qb + (long)e*8);
    *(uint4*)&k_lds[row][c4] = *(const uint4*)(kb + (long)e*8);
    uint4 val = *(const uint4*)(vb + (long)e*8);
    const ushort* u = (const ushort*)&val;
    #pragma unroll
    for (int jj=0;jj<8;jj++) vT[c4+jj][row] = u[jj];
  }
  for (int e = tid; e < 288; e += 256){
    int d = e/9, tap = e%9;
    wl[d][tap] = lepe_w[((long)((layer*2+br)*128 + h*32 + d))*9 + tap];
  }
  if (tid < 32) bl[tid] = lepe_b[(layer*2+br)*128 + h*32 + tid];
  __syncthreads();

  const int wrow = wid*32;
  const float scale = 0.17677669529663689f;
  const int srcE = (lane & 15) | ((lane & 16) << 1);
  const int srcO = srcE + 16;
  const bool hi = (lane >= 32);
  const int HsL = (br==0)?64:2, WsL = (br==0)?2:64;

  #pragma unroll
  for (int mi=0; mi<2; mi++){
    s8v aq = *(const s8v*)&q_lds[wrow + mi*16 + l15][lg*8];
    f4v S[8];
    #pragma unroll
    for (int ni=0; ni<8; ni++){
      s8v bk = *(const s8v*)&k_lds[ni*16 + l15][lg*8];
      f4v z = {0.f,0.f,0.f,0.f};
      S[ni] = __builtin_amdgcn_mfma_f32_16x16x32_bf16(bk, aq, z, 0,0,0);
    }
    float mx = -1e30f;
    #pragma unroll
    for (int ni=0; ni<8; ni++)
      #pragma unroll
      for (int r=0;r<4;r++){ S[ni][r] *= scale; mx = fmaxf(mx, S[ni][r]); }
    mx = fmaxf(mx, __shfl_xor(mx, 16));
    mx = fmaxf(mx, __shfl_xor(mx, 32));
    float sum = 0.f;
    #pragma unroll
    for (int ni=0; ni<8; ni++)
      #pragma unroll
      for (int r=0;r<4;r++){ S[ni][r] = __expf(S[ni][r]-mx); sum += S[ni][r]; }
    sum += __shfl_xor(sum, 16);
    sum += __shfl_xor(sum, 32);
    const float inv = 1.0f / sum;
    unsigned int Alo[8], Ahi[8];
    #pragma unroll
    for (int ni=0; ni<8; ni++){
      Alo[ni] = (unsigned)f2bf(S[ni][0]*inv) | ((unsigned)f2bf(S[ni][1]*inv)<<16);
      Ahi[ni] = (unsigned)f2bf(S[ni][2]*inv) | ((unsigned)f2bf(S[ni][3]*inv)<<16);
    }
    f4v acc2[2] = {{0.f,0.f,0.f,0.f},{0.f,0.f,0.f,0.f}};
    #pragma unroll
    for (int ks=0; ks<4; ks++){
      unsigned e0 = (unsigned)__shfl((int)Alo[2*ks],   srcE);
      unsigned e1 = (unsigned)__shfl((int)Ahi[2*ks],   srcE);
      unsigned e2 = (unsigned)__shfl((int)Alo[2*ks+1], srcE);
      unsigned e3 = (unsigned)__shfl((int)Ahi[2*ks+1], srcE);
      unsigned o0 = (unsigned)__shfl((int)Alo[2*ks],   srcO);
      unsigned o1 = (unsigned)__shfl((int)Ahi[2*ks],   srcO);
      unsigned o2 = (unsigned)__shfl((int)Alo[2*ks+1], srcO);
      unsigned o3 = (unsigned)__shfl((int)Ahi[2*ks+1], srcO);
      union { unsigned u[4]; s8v v; } ap;
      ap.u[0] = hi?e2:e0; ap.u[1] = hi?e3:e1; ap.u[2] = hi?o2:o0; ap.u[3] = hi?o3:o1;
      #pragma unroll
      for (int di=0; di<2; di++){
        s8v bv = *(const s8v*)&vT[di*16 + l15][ks*32 + lg*8];
        acc2[di] = __builtin_amdgcn_mfma_f32_16x16x32_bf16(ap.v, bv, acc2[di], 0,0,0);
      }
    }
    #pragma unroll
    for (int di=0; di<2; di++)
      #pragma unroll
      for (int r=0;r<4;r++){
        int s = wrow + mi*16 + lg*4 + r;
        int d = di*16 + l15;
        float v = acc2[di][r] + bl[d];
        int hs, ws2;
        if (br==0){ hs = s>>1; ws2 = s&1; }
        else      { hs = s>>6; ws2 = s&63; }
        #pragma unroll
        for (int a=-1;a<=1;a++)
          #pragma unroll
          for (int bb=-1;bb<=1;bb++){
            int h2 = hs+a, w2 = ws2+bb;
            if (h2>=0 && h2<HsL && w2>=0 && w2<WsL){
              int s2 = h2*WsL + w2;
              v += wl[d][(a+1)*3 + (bb+1)] * bf2f(vT[d][s2]);
            }
          }
        int y, x;
        if (br==0){ y = s>>1; x = (w<<1)|(s&1); }
        else      { y = (w<<1)|(s>>6); x = s&63; }
        long tok = ((long)b*64 + y)*64 + x;
        ATT[tok*256 + choff + d] = f2bf(v);
      }
  }
}

extern "C" void kernel_launch(void* const* d_in, const int* in_sizes, int n_in,
                              void* d_out, int out_size, void* d_ws, size_t ws_size,
                              hipStream_t stream)
{
  (void)in_sizes; (void)n_in; (void)out_size;
  const float* x1     = (const float*)d_in[0];
  const float* x2     = (const float*)d_in[1];
  const float* conv_w = (const float*)d_in[2];
  const float* conv_b = (const float*)d_in[3];
  const float* bn_g   = (const float*)d_in[4];
  const float* bn_b   = (const float*)d_in[5];
  const float* bn_m   = (const float*)d_in[6];
  const float* bn_v   = (const float*)d_in[7];
  const float* ln0_g  = (const float*)d_in[8];
  const float* ln0_b  = (const float*)d_in[9];
  const float* n1_g   = (const float*)d_in[10];
  const float* n1_b   = (const float*)d_in[11];
  const float* qkv_w  = (const float*)d_in[12];
  const float* lepe_w = (const float*)d_in[13];
  const float* lepe_b = (const float*)d_in[14];
  const float* proj_w = (const float*)d_in[15];
  const float* proj_b = (const float*)d_in[16];
  const float* n2_g   = (const float*)d_in[17];
  const float* n2_b   = (const float*)d_in[18];
  const float* fc1_w  = (const float*)d_in[19];
  const float* fc1_b  = (const float*)d_in[20];
  const float* fc2_w  = (const float*)d_in[21];
  const float* fc2_b  = (const float*)d_in[22];

  if (ws_size < 121767936ULL){
    hipMemsetAsync(d_out, 0, (size_t)out_size*4, stream);
    return;
  }

  // ---- workspace (audited: no in-place read/write, all lifetimes disjoint) ----
  char* ws = (char*)d_ws;
  ushort* Xin  = (ushort*)ws;
  ushort* QKVb = (ushort*)ws;
  ushort* H1b  = (ushort*)ws;
  ushort* ATTb = (ushort*)(ws + 50331648);
  float*  T    = (float*)(ws + 67108864);
  ushort* Xb   = (ushort*)(ws + 100663296);
  size_t off = 117440512;
  ushort* Wc   = (ushort*)(ws + off); off += 1179648;
  ushort* Wq   = (ushort*)(ws + off); off += 786432;
  ushort* Wp   = (ushort*)(ws + off); off += 262144;
  ushort* W1   = (ushort*)(ws + off); off += 1048576;
  ushort* W2   = (ushort*)(ws + off); off += 1048576;
  float*  scv  = (float*)(ws + off);  off += 1024;
  float*  shv  = (float*)(ws + off);  off += 1024;

  hipMemsetAsync(Xin, 0, (size_t)8*66*66*256*2, stream);
  repack_in_k<<<dim3(64,8), 256, 0, stream>>>(x1, x2, Xin);
  prep_k<<<1024, 256, 0, stream>>>(conv_w, qkv_w, proj_w, fc1_w, fc2_w,
                                   conv_b, bn_g, bn_b, bn_m, bn_v,
                                   Wc, Wq, Wp, W1, W2, scv, shv);

  // fused conv+BN+LN0+n1(layer0): -> T, Xb
  gemm_conv<<<512,256,0,stream>>>(Xin, Wc, scv, shv, T, ln0_g, ln0_b, n1_g, n1_b, Xb);

  for (int i=0;i<2;i++){
    gemm_qkv<<<dim3(256,6),256,0,stream>>>(Xb, Wq + (long)i*196608, QKVb, 256);
    attn_k<<<dim3(128,8,2),256,0,stream>>>(QKVb, ATTb, lepe_w, lepe_b, i);
    gemm_res<1><<<512,256,0,stream>>>(ATTb, Wp + (long)i*65536, proj_b + i*256,
                                      T, n2_g + i*256, n2_b + i*256, Xb, nullptr, 256);
    gemm_fc1<<<dim3(256,8),256,0,stream>>>(Xb, W1 + (long)i*262144, fc1_b + i*1024, H1b, 1024, 256);
    if (i == 0){
      gemm_res<1><<<512,256,0,stream>>>(H1b, W2, fc2_b,
                                        T, n1_g + 256, n1_b + 256, Xb, nullptr, 1024);
    } else {
      gemm_res<3><<<512,256,0,stream>>>(H1b, W2 + 262144, fc2_b + 256,
                                        T, nullptr, nullptr, nullptr, (float*)d_out, 1024);
    }
  }
}

// Round 22
// 433.194 us; speedup vs baseline: 1.0192x; 1.0192x over previous
//
#include <hip/hip_runtime.h>
#include <hip/hip_bf16.h>

#define EPSV 1e-5f

using s8v = __attribute__((ext_vector_type(8))) short;
using f4v = __attribute__((ext_vector_type(4))) float;

__device__ __forceinline__ float bf2f(ushort u){
  union { unsigned int i; float f; } x; x.i = ((unsigned int)u)<<16; return x.f;
}
__device__ __forceinline__ ushort f2bf(float f){
  union { float f; unsigned int i; } x; x.f = f;
  unsigned int r = x.i + 0x7FFFu + ((x.i>>16)&1u);
  return (ushort)(r>>16);
}
__device__ __forceinline__ float wsum(float s){
  #pragma unroll
  for (int m=1;m<64;m<<=1) s += __shfl_xor(s, m);
  return s;
}
__device__ __forceinline__ float gelu_f(float t){
  return 0.5f*t*(1.0f + erff(t*0.70710678118654752f));
}

__device__ __forceinline__ void gload16(const void* g, void* l){
  __builtin_amdgcn_global_load_lds((__attribute__((address_space(1))) void*)g,
                                   (__attribute__((address_space(3))) void*)l, 16, 0, 0);
}

// ---------------- input repack: NCHW f32 (x1|x2) -> padded NHWC bf16 [8][66][66][256] ----------------
__global__ __launch_bounds__(256) void repack_in_k(const float* __restrict__ x1,
                                                   const float* __restrict__ x2,
                                                   ushort* __restrict__ Xin){
  __shared__ ushort tile[256][66];
  const int y = blockIdx.x, b = blockIdx.y, tid = threadIdx.x;
  const int xl = tid & 63, cq = tid >> 6;
  for (int it=0; it<64; it++){
    int ci = it*4 + cq;
    float v;
    if (ci < 128) v = x1[(((long)b*128 + ci)*64 + y)*64 + xl];
    else          v = x2[(((long)b*128 + (ci-128))*64 + y)*64 + xl];
    tile[ci][xl] = f2bf(v);
  }
  __syncthreads();
  for (int x=0; x<64; x++){
    Xin[(((long)b*66 + (y+1))*66 + (x+1))*256 + tid] = tile[tid][x];
  }
}

// ---------------- unified weight prep: all repacks + BN fold in ONE launch ----------------
__global__ void prep_k(const float* __restrict__ conv_w, const float* __restrict__ qkv_w,
                       const float* __restrict__ proj_w, const float* __restrict__ fc1_w,
                       const float* __restrict__ fc2_w, const float* __restrict__ conv_b,
                       const float* __restrict__ bn_g, const float* __restrict__ bn_b,
                       const float* __restrict__ bn_m, const float* __restrict__ bn_v,
                       ushort* __restrict__ Wc, ushort* __restrict__ Wq, ushort* __restrict__ Wp,
                       ushort* __restrict__ W1, ushort* __restrict__ W2,
                       float* __restrict__ scv, float* __restrict__ shv)
{
  const long total = 589824L + 393216 + 131072 + 524288 + 524288 + 256;
  for (long idx = (long)blockIdx.x*256 + threadIdx.x; idx < total; idx += (long)gridDim.x*256){
    long e = idx;
    if (e < 589824){
      int co = (int)(e / 2304), kk = (int)(e % 2304);
      int dd = kk >> 8, ci = kk & 255;
      Wc[e] = f2bf(conv_w[((long)(co*256 + ci))*9 + dd]);
      continue;
    }
    e -= 589824;
    if (e < 393216){
      int l = (int)(e / 196608), r = (int)(e % 196608);
      int k = r / 768, n = r % 768;
      Wq[(long)l*196608 + (long)n*256 + k] = f2bf(qkv_w[(long)l*196608 + r]);
      continue;
    }
    e -= 393216;
    if (e < 131072){
      int l = (int)(e / 65536), r = (int)(e % 65536);
      int k = r >> 8, n = r & 255;
      Wp[(long)l*65536 + n*256 + k] = f2bf(proj_w[(long)l*65536 + r]);
      continue;
    }
    e -= 131072;
    if (e < 524288){
      int l = (int)(e / 262144), r = (int)(e % 262144);
      int k = r >> 10, n = r & 1023;
      W1[(long)l*262144 + (long)n*256 + k] = f2bf(fc1_w[(long)l*262144 + r]);
      continue;
    }
    e -= 524288;
    if (e < 524288){
      int l = (int)(e / 262144), r = (int)(e % 262144);
      int k = r >> 8, n = r & 255;
      W2[(long)l*262144 + (long)n*1024 + k] = f2bf(fc2_w[(long)l*262144 + r]);
      continue;
    }
    e -= 524288;
    {
      int n = (int)e;
      float s = bn_g[n] * rsqrtf(bn_v[n] + EPSV);
      scv[n] = s;
      shv[n] = (conv_b[n] - bn_m[n])*s + bn_b[n];
    }
  }
}

// ================= conv GEMM (K=2304): BM=64, BN=256, BK=64 double-buffered + swizzled =================
// fused: t=LN0(v*sc+sh) -> T ; Xb = LN_{g2,b2}(t)
__global__ __launch_bounds__(256) void gemm_conv(
    const ushort* __restrict__ Xin, const ushort* __restrict__ Wt,
    const float* __restrict__ sc, const float* __restrict__ sh,
    float* __restrict__ T, const float* __restrict__ g1, const float* __restrict__ b1,
    const float* __restrict__ g2, const float* __restrict__ b2,
    ushort* __restrict__ Xb)
{
  const int K = 2304;
  __shared__ ushort SMEM[40960];
  const int tid = threadIdx.x, wid = tid>>6, lane = tid&63;
  const int m0 = blockIdx.x*64;
  const int l15 = lane&15, lg = lane>>4;
  const int rS = wid*8 + (lane>>3);
  const int cS = (((lane&7) ^ (lane>>3))*8);

  const ushort* pA[2];
  #pragma unroll
  for (int j=0;j<2;j++){
    int t = m0 + j*32 + rS;
    int b = t>>12, y = (t>>6)&63, x = t&63;
    pA[j] = Xin + ((long)((b*66 + y+1)*66) + (x+1))*256 + cS;
  }
  const ushort* pB[8];
  #pragma unroll
  for (int j=0;j<8;j++) pB[j] = Wt + (long)(j*32 + rS)*K + cS;

  auto stage = [&](int buf, int k0){
    ushort* AsB = SMEM + buf*20480;
    ushort* BsB = AsB + 4096;
    int dd = k0 >> 8;
    int dy = dd/3, dx = dd - dy*3;
    int koffA = ((dy-1)*66 + (dx-1))*256 + (k0 & 255);
    #pragma unroll
    for (int j=0;j<2;j++)
      gload16(pA[j] + koffA, (void*)&AsB[(j*256 + wid*64)*8]);
    #pragma unroll
    for (int j=0;j<8;j++)
      gload16(pB[j] + k0, (void*)&BsB[(j*256 + wid*64)*8]);
  };

  f4v acc[4][4] = {};

  int cur = 0;
  stage(0, 0);
  __syncthreads();
  for (int k0=0; k0<K; k0+=64){
    if (k0 + 64 < K) stage(cur^1, k0 + 64);
    const ushort* AsB = SMEM + cur*20480;
    const ushort* BsB = AsB + 4096;
    #pragma unroll
    for (int kk=0; kk<2; kk++){
      s8v a[4], b[4];
      const int kch = ((kk*4 + lg) ^ (l15 & 7))*8;
      #pragma unroll
      for (int mi=0;mi<4;mi++) a[mi] = *(const s8v*)&AsB[(mi*16 + l15)*64 + kch];
      #pragma unroll
      for (int ni=0;ni<4;ni++) b[ni] = *(const s8v*)&BsB[(wid*64 + ni*16 + l15)*64 + kch];
      #pragma unroll
      for (int mi=0;mi<4;mi++)
        #pragma unroll
        for (int ni=0;ni<4;ni++)
          acc[mi][ni] = __builtin_amdgcn_mfma_f32_16x16x32_bf16(a[mi], b[ni], acc[mi][ni], 0,0,0);
    }
    __syncthreads();
    cur ^= 1;
  }

  float* CT = (float*)SMEM;
  #pragma unroll
  for (int mi=0;mi<4;mi++)
    #pragma unroll
    for (int ni=0;ni<4;ni++)
      #pragma unroll
      for (int r=0;r<4;r++)
        CT[(mi*16 + lg*4 + r)*256 + wid*64 + ni*16 + l15] = acc[mi][ni][r];
  __syncthreads();

  const int c0 = lane*4;
  const float4 scv4 = *(const float4*)&sc[c0], shv4 = *(const float4*)&sh[c0];
  const float4 g1v = *(const float4*)&g1[c0], b1v = *(const float4*)&b1[c0];
  const float4 g2v = *(const float4*)&g2[c0], b2v = *(const float4*)&b2[c0];

  for (int t=0; t<16; t++){
    const int r = wid*16 + t;
    const long gmr = m0 + r;
    float4 v = *(float4*)&CT[r*256 + c0];
    float4 t4;
    t4.x = v.x*scv4.x + shv4.x; t4.y = v.y*scv4.y + shv4.y;
    t4.z = v.z*scv4.z + shv4.z; t4.w = v.w*scv4.w + shv4.w;
    float mu = wsum(t4.x+t4.y+t4.z+t4.w) * (1.0f/256.0f);
    float d0=t4.x-mu, d1=t4.y-mu, d2=t4.z-mu, d3=t4.w-mu;
    float rs = rsqrtf(wsum(d0*d0+d1*d1+d2*d2+d3*d3)*(1.0f/256.0f) + EPSV);
    float u0 = d0*rs*g1v.x + b1v.x, u1 = d1*rs*g1v.y + b1v.y;
    float u2 = d2*rs*g1v.z + b1v.z, u3 = d3*rs*g1v.w + b1v.w;
    float4 u = {u0,u1,u2,u3};
    *(float4*)&T[gmr*256 + c0] = u;
    float mu2 = wsum(u0+u1+u2+u3) * (1.0f/256.0f);
    float e0=u0-mu2, e1=u1-mu2, e2=u2-mu2, e3=u3-mu2;
    float rs2 = rsqrtf(wsum(e0*e0+e1*e1+e2*e2+e3*e3)*(1.0f/256.0f) + EPSV);
    ushort4 o; o.x=f2bf(e0*rs2*g2v.x + b2v.x); o.y=f2bf(e1*rs2*g2v.y + b2v.y);
    o.z=f2bf(e2*rs2*g2v.z + b2v.z); o.w=f2bf(e3*rs2*g2v.w + b2v.w);
    *(ushort4*)&Xb[gmr*256 + c0] = o;
  }
}

// ================= residual GEMM: BM=64, BN=256, BK=32 DOUBLE-buffered (40KB), 2-pass epilogue ====
template<int EPI>
__global__ __launch_bounds__(256) void gemm_res(
    const ushort* __restrict__ A, const ushort* __restrict__ Wt, const float* __restrict__ bias,
    float* __restrict__ T, const float* __restrict__ g1, const float* __restrict__ b1,
    ushort* __restrict__ Xb, float* __restrict__ dout, int K)
{
  __shared__ ushort SMEM[20480];
  const int tid = threadIdx.x, wid = tid>>6, lane = tid&63;
  const int m0 = blockIdx.x*64;
  const int l15 = lane&15, lg = lane>>4;
  const int rowS = wid*16 + (lane>>2);
  const int cSrc = (((lane&3) ^ ((lane>>3)&3))*8);

  const ushort* pA = A + (long)(m0 + rowS)*K + cSrc;
  const ushort* pB[4];
  #pragma unroll
  for (int j=0;j<4;j++) pB[j] = Wt + (long)(j*64 + rowS)*K + cSrc;

  auto stage = [&](int buf, int k0){
    ushort* S = SMEM + buf*10240;
    gload16(pA + k0, (void*)&S[tid*8]);
    #pragma unroll
    for (int j=0;j<4;j++)
      gload16(pB[j] + k0, (void*)&S[2048 + j*2048 + tid*8]);
  };

  f4v acc[4][4] = {};

  int cur = 0;
  stage(0, 0);
  __syncthreads();
  for (int k0=0; k0<K; k0+=32){
    if (k0 + 32 < K) stage(cur^1, k0 + 32);
    const ushort* As_ = SMEM + cur*10240;
    const ushort* Bs_ = As_ + 2048;
    const int kch = (lg ^ ((l15>>1)&3))*8;
    s8v a[4], b[4];
    #pragma unroll
    for (int mi=0;mi<4;mi++) a[mi] = *(const s8v*)&As_[(mi*16 + l15)*32 + kch];
    #pragma unroll
    for (int ni=0;ni<4;ni++) b[ni] = *(const s8v*)&Bs_[(wid*64 + ni*16 + l15)*32 + kch];
    #pragma unroll
    for (int mi=0;mi<4;mi++)
      #pragma unroll
      for (int ni=0;ni<4;ni++)
        acc[mi][ni] = __builtin_amdgcn_mfma_f32_16x16x32_bf16(a[mi], b[ni], acc[mi][ni], 0,0,0);
    __syncthreads();
    cur ^= 1;
  }

  float* CT = (float*)SMEM;
  const int c0 = lane*4;
  const float4 bias4 = *(const float4*)&bias[c0];
  float4 g1v, b1v;
  if (EPI==1){ g1v = *(const float4*)&g1[c0]; b1v = *(const float4*)&b1[c0]; }
  const int b_ = m0>>12, y_ = (m0>>6)&63;

  #pragma unroll
  for (int p=0; p<2; p++){
    #pragma unroll
    for (int mi=2*p; mi<2*p+2; mi++)
      #pragma unroll
      for (int ni=0;ni<4;ni++)
        #pragma unroll
        for (int r=0;r<4;r++)
          CT[((mi-2*p)*16 + lg*4 + r)*256 + wid*64 + ni*16 + l15] = acc[mi][ni][r];
    __syncthreads();
    for (int t=0; t<8; t++){
      const int r = wid*8 + t;
      const long gmr = m0 + p*32 + r;
      float4 v = *(float4*)&CT[r*256 + c0];
      float4 rv = *(float4*)&T[gmr*256 + c0];
      float4 t4;
      t4.x = rv.x + v.x + bias4.x; t4.y = rv.y + v.y + bias4.y;
      t4.z = rv.z + v.z + bias4.z; t4.w = rv.w + v.w + bias4.w;
      if (EPI==3){
        *(float4*)&CT[r*256 + c0] = t4;
      } else {
        *(float4*)&T[gmr*256 + c0] = t4;
        float mu = wsum(t4.x+t4.y+t4.z+t4.w) * (1.0f/256.0f);
        float d0=t4.x-mu, d1=t4.y-mu, d2=t4.z-mu, d3=t4.w-mu;
        float rs = rsqrtf(wsum(d0*d0+d1*d1+d2*d2+d3*d3)*(1.0f/256.0f) + EPSV);
        ushort4 o; o.x=f2bf(d0*rs*g1v.x + b1v.x); o.y=f2bf(d1*rs*g1v.y + b1v.y);
        o.z=f2bf(d2*rs*g1v.z + b1v.z); o.w=f2bf(d3*rs*g1v.w + b1v.w);
        *(ushort4*)&Xb[gmr*256 + c0] = o;
      }
    }
    __syncthreads();
    if (EPI==3){
      float* obase = dout + (long)b_*524288 + (long)y_*64 + p*32;
      for (int it=0; it<32; it++){
        int e = it*256 + tid;
        int c = e>>5, xl = e&31;
        obase[(long)(c>>7)*4194304 + (long)(c&127)*4096 + xl] = CT[xl*256 + c];
      }
      __syncthreads();
    }
  }
}

// ---------------- fc1 GEMM (N=1024): BM=BN=128, BK=32 DOUBLE-buffered (32KB), bias+GELU ----------------
#define BM 128
#define BN 128
__global__ __launch_bounds__(256) void gemm_fc1(
    const ushort* __restrict__ A,
    const ushort* __restrict__ Wt, const float* __restrict__ bias,
    ushort* __restrict__ outb, int N, int K)
{
  __shared__ ushort SMEM[16384];
  const int tid = threadIdx.x, wid = tid>>6, lane = tid&63;
  const int m0 = blockIdx.x*BM, n0 = blockIdx.y*BN;
  const int wm = (wid>>1)*64, wn = (wid&1)*64;
  const int l15 = lane&15, lg = lane>>4;
  const int rowS = wid*16 + (lane>>2);
  const int cSrc = (((lane&3) ^ ((lane>>3)&3))*8);

  const ushort* pA[2];
  #pragma unroll
  for (int j=0;j<2;j++) pA[j] = A + (long)(m0 + j*64 + rowS)*K + cSrc;
  const ushort* pB[2];
  #pragma unroll
  for (int j=0;j<2;j++) pB[j] = Wt + (long)(n0 + j*64 + rowS)*K + cSrc;

  auto stage = [&](int buf, int k0){
    ushort* S = SMEM + buf*8192;
    #pragma unroll
    for (int j=0;j<2;j++)
      gload16(pA[j] + k0, (void*)&S[j*2048 + tid*8]);
    #pragma unroll
    for (int j=0;j<2;j++)
      gload16(pB[j] + k0, (void*)&S[4096 + j*2048 + tid*8]);
  };

  f4v acc[4][4] = {};

  int cur = 0;
  stage(0, 0);
  __syncthreads();
  for (int k0=0; k0<K; k0+=32){
    if (k0 + 32 < K) stage(cur^1, k0 + 32);
    const ushort* As_ = SMEM + cur*8192;
    const ushort* Bs_ = As_ + 4096;
    const int kch = (lg ^ ((l15>>1)&3))*8;
    s8v a[4], b[4];
    #pragma unroll
    for (int mi=0;mi<4;mi++) a[mi] = *(const s8v*)&As_[(wm + mi*16 + l15)*32 + kch];
    #pragma unroll
    for (int ni=0;ni<4;ni++) b[ni] = *(const s8v*)&Bs_[(wn + ni*16 + l15)*32 + kch];
    #pragma unroll
    for (int mi=0;mi<4;mi++)
      #pragma unroll
      for (int ni=0;ni<4;ni++)
        acc[mi][ni] = __builtin_amdgcn_mfma_f32_16x16x32_bf16(a[mi], b[ni], acc[mi][ni], 0,0,0);
    __syncthreads();
    cur ^= 1;
  }

  float* CT = (float*)SMEM;
  #pragma unroll
  for (int p=0; p<2; p++){
    if ((wid>>1) == p){
      #pragma unroll
      for (int mi=0;mi<4;mi++)
        #pragma unroll
        for (int ni=0;ni<4;ni++)
          #pragma unroll
          for (int r=0;r<4;r++)
            CT[(mi*16 + lg*4 + r)*128 + wn + ni*16 + l15] = acc[mi][ni][r];
    }
    __syncthreads();
    #pragma unroll
    for (int it=0; it<8; it++){
      int e = it*256 + tid;
      int row = e >> 5;
      int c4 = e & 31;
      float4 v = *(float4*)&CT[row*128 + c4*4];
      int gm = m0 + p*64 + row;
      int gn = n0 + c4*4;
      float4 bv = *(const float4*)&bias[gn];
      float t0 = gelu_f(v.x + bv.x), t1 = gelu_f(v.y + bv.y);
      float t2 = gelu_f(v.z + bv.z), t3 = gelu_f(v.w + bv.w);
      ushort4 u; u.x=f2bf(t0); u.y=f2bf(t1); u.z=f2bf(t2); u.w=f2bf(t3);
      *(ushort4*)&outb[(long)gm*N + gn] = u;
    }
    __syncthreads();
  }
}

// ---------------- qkv GEMM (N=768): BM=BN=128, BK=32 DOUBLE-buffered (32KB), window-store ----------------
__global__ __launch_bounds__(256) void gemm_qkv(
    const ushort* __restrict__ A,
    const ushort* __restrict__ Wt,
    ushort* __restrict__ outb, int K)
{
  __shared__ ushort SMEM[16384];
  const int tid = threadIdx.x, wid = tid>>6, lane = tid&63;
  const int m0 = blockIdx.x*BM, n0 = blockIdx.y*BN;
  const int wm = (wid>>1)*64, wn = (wid&1)*64;
  const int l15 = lane&15, lg = lane>>4;
  const int rowS = wid*16 + (lane>>2);
  const int cSrc = (((lane&3) ^ ((lane>>3)&3))*8);

  const ushort* pA[2];
  #pragma unroll
  for (int j=0;j<2;j++) pA[j] = A + (long)(m0 + j*64 + rowS)*K + cSrc;
  const ushort* pB[2];
  #pragma unroll
  for (int j=0;j<2;j++) pB[j] = Wt + (long)(n0 + j*64 + rowS)*K + cSrc;

  auto stage = [&](int buf, int k0){
    ushort* S = SMEM + buf*8192;
    #pragma unroll
    for (int j=0;j<2;j++)
      gload16(pA[j] + k0, (void*)&S[j*2048 + tid*8]);
    #pragma unroll
    for (int j=0;j<2;j++)
      gload16(pB[j] + k0, (void*)&S[4096 + j*2048 + tid*8]);
  };

  f4v acc[4][4] = {};

  int cur = 0;
  stage(0, 0);
  __syncthreads();
  for (int k0=0; k0<K; k0+=32){
    if (k0 + 32 < K) stage(cur^1, k0 + 32);
    const ushort* As_ = SMEM + cur*8192;
    const ushort* Bs_ = As_ + 4096;
    const int kch = (lg ^ ((l15>>1)&3))*8;
    s8v a[4], b[4];
    #pragma unroll
    for (int mi=0;mi<4;mi++) a[mi] = *(const s8v*)&As_[(wm + mi*16 + l15)*32 + kch];
    #pragma unroll
    for (int ni=0;ni<4;ni++) b[ni] = *(const s8v*)&Bs_[(wn + ni*16 + l15)*32 + kch];
    #pragma unroll
    for (int mi=0;mi<4;mi++)
      #pragma unroll
      for (int ni=0;ni<4;ni++)
        acc[mi][ni] = __builtin_amdgcn_mfma_f32_16x16x32_bf16(a[mi], b[ni], acc[mi][ni], 0,0,0);
    __syncthreads();
    cur ^= 1;
  }

  ushort* CB = SMEM;
  #pragma unroll
  for (int ni=0;ni<4;ni++){
    const int c = wn + ni*16 + l15;
    const int j = c>>3, ce = c&7;
    #pragma unroll
    for (int mi=0;mi<4;mi++)
      #pragma unroll
      for (int r=0;r<4;r++){
        const int row = wm + mi*16 + lg*4 + r;
        CB[row*128 + (((j ^ (row&7))<<3) | ce)] = f2bf(acc[mi][ni][r]);
      }
  }
  __syncthreads();

  const int tile = n0 >> 8;
  const int brq  = (n0 >> 7) & 1;
  const int b_   = m0 >> 12;
  const int Y0   = (m0 >> 6) & 63;
  if (brq == 0){
    #pragma unroll
    for (int it=0; it<8; it++){
      int g = it*256 + tid;
      int seg = g >> 4, q = g & 15;
      int h = seg >> 5, wv = seg & 31;
      int svi = q >> 2, c8 = q & 3;
      int gm_local = (svi>>1)*64 + wv*2 + (svi&1);
      int jc = h*4 + c8;
      uint4 v = *(uint4*)&CB[gm_local*128 + ((jc ^ (gm_local&7))<<3)];
      long rowb = ((long)(tile*2)*4 + h)*32768L + ((long)b_*32 + wv)*128 + (Y0*2 + svi);
      *(uint4*)&outb[rowb*32 + c8*8] = v;
    }
  } else {
    const int wv = Y0 >> 1;
    #pragma unroll
    for (int it=0; it<8; it++){
      int g = it*256 + tid;
      int h = g >> 9, rem = g & 511, sv = rem >> 2, c8 = rem & 3;
      int jc = h*4 + c8;
      uint4 v = *(uint4*)&CB[sv*128 + ((jc ^ (sv&7))<<3)];
      long rowb = ((long)(tile*2 + 1)*4 + h)*32768L + ((long)b_*32 + wv)*128 + sv;
      *(uint4*)&outb[rowb*32 + c8*8] = v;
    }
  }
}

// ---------------- stripe-window attention + LePE (swapped-QK^T, in-register P) ----------------
__global__ __launch_bounds__(256) void attn_k(
    const ushort* __restrict__ QKVw, ushort* __restrict__ ATT,
    const float* __restrict__ lepe_w, const float* __restrict__ lepe_b, int layer)
{
  __shared__ ushort q_lds[128][36];
  __shared__ ushort k_lds[128][36];
  __shared__ ushort vT[32][132];
  __shared__ float wl[32][9];
  __shared__ float bl[32];
  const int tid = threadIdx.x, wid = tid>>6, lane = tid&63;
  const int b = blockIdx.y;
  const int br = blockIdx.z;
  const int w = blockIdx.x>>2, h = blockIdx.x&3;
  const int choff = br*128 + h*32;
  const int l15 = lane&15, lg = lane>>4;

  const long rowbase = ((long)b*32 + w)*128;
  const ushort* qb = QKVw + (((long)(0*2+br)*4 + h)*32768L + rowbase)*32;
  const ushort* kb = QKVw + (((long)(1*2+br)*4 + h)*32768L + rowbase)*32;
  const ushort* vb = QKVw + (((long)(2*2+br)*4 + h)*32768L + rowbase)*32;

  for (int e = tid; e < 512; e += 256){
    int row = e>>2, c4 = (e&3)*8;
    *(uint4*)&q_lds[row][c4] = *(const uint4*)(qb + (long)e*8);
    *(uint4*)&k_lds[row][c4] = *(const uint4*)(kb + (long)e*8);
    uint4 val = *(const uint4*)(vb + (long)e*8);
    const ushort* u = (const ushort*)&val;
    #pragma unroll
    for (int jj=0;jj<8;jj++) vT[c4+jj][row] = u[jj];
  }
  for (int e = tid; e < 288; e += 256){
    int d = e/9, tap = e%9;
    wl[d][tap] = lepe_w[((long)((layer*2+br)*128 + h*32 + d))*9 + tap];
  }
  if (tid < 32) bl[tid] = lepe_b[(layer*2+br)*128 + h*32 + tid];
  __syncthreads();

  const int wrow = wid*32;
  const float scale = 0.17677669529663689f;
  const int srcE = (lane & 15) | ((lane & 16) << 1);
  const int srcO = srcE + 16;
  const bool hi = (lane >= 32);
  const int HsL = (br==0)?64:2, WsL = (br==0)?2:64;

  #pragma unroll
  for (int mi=0; mi<2; mi++){
    s8v aq = *(const s8v*)&q_lds[wrow + mi*16 + l15][lg*8];
    f4v S[8];
    #pragma unroll
    for (int ni=0; ni<8; ni++){
      s8v bk = *(const s8v*)&k_lds[ni*16 + l15][lg*8];
      f4v z = {0.f,0.f,0.f,0.f};
      S[ni] = __builtin_amdgcn_mfma_f32_16x16x32_bf16(bk, aq, z, 0,0,0);
    }
    float mx = -1e30f;
    #pragma unroll
    for (int ni=0; ni<8; ni++)
      #pragma unroll
      for (int r=0;r<4;r++){ S[ni][r] *= scale; mx = fmaxf(mx, S[ni][r]); }
    mx = fmaxf(mx, __shfl_xor(mx, 16));
    mx = fmaxf(mx, __shfl_xor(mx, 32));
    float sum = 0.f;
    #pragma unroll
    for (int ni=0; ni<8; ni++)
      #pragma unroll
      for (int r=0;r<4;r++){ S[ni][r] = __expf(S[ni][r]-mx); sum += S[ni][r]; }
    sum += __shfl_xor(sum, 16);
    sum += __shfl_xor(sum, 32);
    const float inv = 1.0f / sum;
    unsigned int Alo[8], Ahi[8];
    #pragma unroll
    for (int ni=0; ni<8; ni++){
      Alo[ni] = (unsigned)f2bf(S[ni][0]*inv) | ((unsigned)f2bf(S[ni][1]*inv)<<16);
      Ahi[ni] = (unsigned)f2bf(S[ni][2]*inv) | ((unsigned)f2bf(S[ni][3]*inv)<<16);
    }
    f4v acc2[2] = {{0.f,0.f,0.f,0.f},{0.f,0.f,0.f,0.f}};
    #pragma unroll
    for (int ks=0; ks<4; ks++){
      unsigned e0 = (unsigned)__shfl((int)Alo[2*ks],   srcE);
      unsigned e1 = (unsigned)__shfl((int)Ahi[2*ks],   srcE);
      unsigned e2 = (unsigned)__shfl((int)Alo[2*ks+1], srcE);
      unsigned e3 = (unsigned)__shfl((int)Ahi[2*ks+1], srcE);
      unsigned o0 = (unsigned)__shfl((int)Alo[2*ks],   srcO);
      unsigned o1 = (unsigned)__shfl((int)Ahi[2*ks],   srcO);
      unsigned o2 = (unsigned)__shfl((int)Alo[2*ks+1], srcO);
      unsigned o3 = (unsigned)__shfl((int)Ahi[2*ks+1], srcO);
      union { unsigned u[4]; s8v v; } ap;
      ap.u[0] = hi?e2:e0; ap.u[1] = hi?e3:e1; ap.u[2] = hi?o2:o0; ap.u[3] = hi?o3:o1;
      #pragma unroll
      for (int di=0; di<2; di++){
        s8v bv = *(const s8v*)&vT[di*16 + l15][ks*32 + lg*8];
        acc2[di] = __builtin_amdgcn_mfma_f32_16x16x32_bf16(ap.v, bv, acc2[di], 0,0,0);
      }
    }
    #pragma unroll
    for (int di=0; di<2; di++)
      #pragma unroll
      for (int r=0;r<4;r++){
        int s = wrow + mi*16 + lg*4 + r;
        int d = di*16 + l15;
        float v = acc2[di][r] + bl[d];
        int hs, ws2;
        if (br==0){ hs = s>>1; ws2 = s&1; }
        else      { hs = s>>6; ws2 = s&63; }
        #pragma unroll
        for (int a=-1;a<=1;a++)
          #pragma unroll
          for (int bb=-1;bb<=1;bb++){
            int h2 = hs+a, w2 = ws2+bb;
            if (h2>=0 && h2<HsL && w2>=0 && w2<WsL){
              int s2 = h2*WsL + w2;
              v += wl[d][(a+1)*3 + (bb+1)] * bf2f(vT[d][s2]);
            }
          }
        int y, x;
        if (br==0){ y = s>>1; x = (w<<1)|(s&1); }
        else      { y = (w<<1)|(s>>6); x = s&63; }
        long tok = ((long)b*64 + y)*64 + x;
        ATT[tok*256 + choff + d] = f2bf(v);
      }
  }
}

extern "C" void kernel_launch(void* const* d_in, const int* in_sizes, int n_in,
                              void* d_out, int out_size, void* d_ws, size_t ws_size,
                              hipStream_t stream)
{
  (void)in_sizes; (void)n_in; (void)out_size;
  const float* x1     = (const float*)d_in[0];
  const float* x2     = (const float*)d_in[1];
  const float* conv_w = (const float*)d_in[2];
  const float* conv_b = (const float*)d_in[3];
  const float* bn_g   = (const float*)d_in[4];
  const float* bn_b   = (const float*)d_in[5];
  const float* bn_m   = (const float*)d_in[6];
  const float* bn_v   = (const float*)d_in[7];
  const float* ln0_g  = (const float*)d_in[8];
  const float* ln0_b  = (const float*)d_in[9];
  const float* n1_g   = (const float*)d_in[10];
  const float* n1_b   = (const float*)d_in[11];
  const float* qkv_w  = (const float*)d_in[12];
  const float* lepe_w = (const float*)d_in[13];
  const float* lepe_b = (const float*)d_in[14];
  const float* proj_w = (const float*)d_in[15];
  const float* proj_b = (const float*)d_in[16];
  const float* n2_g   = (const float*)d_in[17];
  const float* n2_b   = (const float*)d_in[18];
  const float* fc1_w  = (const float*)d_in[19];
  const float* fc1_b  = (const float*)d_in[20];
  const float* fc2_w  = (const float*)d_in[21];
  const float* fc2_b  = (const float*)d_in[22];

  if (ws_size < 121767936ULL){
    hipMemsetAsync(d_out, 0, (size_t)out_size*4, stream);
    return;
  }

  // ---- workspace (audited: no in-place read/write, all lifetimes disjoint) ----
  char* ws = (char*)d_ws;
  ushort* Xin  = (ushort*)ws;
  ushort* QKVb = (ushort*)ws;
  ushort* H1b  = (ushort*)ws;
  ushort* ATTb = (ushort*)(ws + 50331648);
  float*  T    = (float*)(ws + 67108864);
  ushort* Xb   = (ushort*)(ws + 100663296);
  size_t off = 117440512;
  ushort* Wc   = (ushort*)(ws + off); off += 1179648;
  ushort* Wq   = (ushort*)(ws + off); off += 786432;
  ushort* Wp   = (ushort*)(ws + off); off += 262144;
  ushort* W1   = (ushort*)(ws + off); off += 1048576;
  ushort* W2   = (ushort*)(ws + off); off += 1048576;
  float*  scv  = (float*)(ws + off);  off += 1024;
  float*  shv  = (float*)(ws + off);  off += 1024;

  hipMemsetAsync(Xin, 0, (size_t)8*66*66*256*2, stream);
  repack_in_k<<<dim3(64,8), 256, 0, stream>>>(x1, x2, Xin);
  prep_k<<<1024, 256, 0, stream>>>(conv_w, qkv_w, proj_w, fc1_w, fc2_w,
                                   conv_b, bn_g, bn_b, bn_m, bn_v,
                                   Wc, Wq, Wp, W1, W2, scv, shv);

  // fused conv+BN+LN0+n1(layer0): -> T, Xb
  gemm_conv<<<512,256,0,stream>>>(Xin, Wc, scv, shv, T, ln0_g, ln0_b, n1_g, n1_b, Xb);

  for (int i=0;i<2;i++){
    gemm_qkv<<<dim3(256,6),256,0,stream>>>(Xb, Wq + (long)i*196608, QKVb, 256);
    attn_k<<<dim3(128,8,2),256,0,stream>>>(QKVb, ATTb, lepe_w, lepe_b, i);
    gemm_res<1><<<512,256,0,stream>>>(ATTb, Wp + (long)i*65536, proj_b + i*256,
                                      T, n2_g + i*256, n2_b + i*256, Xb, nullptr, 256);
    gemm_fc1<<<dim3(256,8),256,0,stream>>>(Xb, W1 + (long)i*262144, fc1_b + i*1024, H1b, 1024, 256);
    if (i == 0){
      gemm_res<1><<<512,256,0,stream>>>(H1b, W2, fc2_b,
                                        T, n1_g + 256, n1_b + 256, Xb, nullptr, 1024);
    } else {
      gemm_res<3><<<512,256,0,stream>>>(H1b, W2 + 262144, fc2_b + 256,
                                        T, nullptr, nullptr, nullptr, (float*)d_out, 1024);
    }
  }
}

// Round 23
// 426.917 us; speedup vs baseline: 1.0341x; 1.0147x over previous
//
#include <hip/hip_runtime.h>
#include <hip/hip_bf16.h>

#define EPSV 1e-5f

using s8v = __attribute__((ext_vector_type(8))) short;
using f4v = __attribute__((ext_vector_type(4))) float;

__device__ __forceinline__ float bf2f(ushort u){
  union { unsigned int i; float f; } x; x.i = ((unsigned int)u)<<16; return x.f;
}
__device__ __forceinline__ ushort f2bf(float f){
  union { float f; unsigned int i; } x; x.f = f;
  unsigned int r = x.i + 0x7FFFu + ((x.i>>16)&1u);
  return (ushort)(r>>16);
}
__device__ __forceinline__ float wsum(float s){
  #pragma unroll
  for (int m=1;m<64;m<<=1) s += __shfl_xor(s, m);
  return s;
}
__device__ __forceinline__ float gelu_f(float t){
  return 0.5f*t*(1.0f + erff(t*0.70710678118654752f));
}

__device__ __forceinline__ void gload16(const void* g, void* l){
  __builtin_amdgcn_global_load_lds((__attribute__((address_space(1))) void*)g,
                                   (__attribute__((address_space(3))) void*)l, 16, 0, 0);
}

// ---------------- input repack: NCHW f32 (x1|x2) -> padded NHWC bf16 [8][66][66][256] ----------------
// Also zeroes the halo border (rows 0/65 fully; cols 0/65 of each interior row) -> no memset needed.
__global__ __launch_bounds__(256) void repack_in_k(const float* __restrict__ x1,
                                                   const float* __restrict__ x2,
                                                   ushort* __restrict__ Xin){
  __shared__ ushort tile[256][66];
  const int y = blockIdx.x, b = blockIdx.y, tid = threadIdx.x;
  const int xl = tid & 63, cq = tid >> 6;
  for (int it=0; it<64; it++){
    int ci = it*4 + cq;
    float v;
    if (ci < 128) v = x1[(((long)b*128 + ci)*64 + y)*64 + xl];
    else          v = x2[(((long)b*128 + (ci-128))*64 + y)*64 + xl];
    tile[ci][xl] = f2bf(v);
  }
  __syncthreads();
  for (int x=0; x<64; x++){
    Xin[(((long)b*66 + (y+1))*66 + (x+1))*256 + tid] = tile[tid][x];
  }
  // halo: cols 0 and 65 of this block's row (y+1)
  Xin[(((long)b*66 + (y+1))*66 + 0)*256 + tid] = 0;
  Xin[(((long)b*66 + (y+1))*66 + 65)*256 + tid] = 0;
  // halo: full top/bottom rows
  if (y == 0){
    for (int xx=0; xx<66; xx++)
      Xin[(((long)b*66 + 0)*66 + xx)*256 + tid] = 0;
  }
  if (y == 63){
    for (int xx=0; xx<66; xx++)
      Xin[(((long)b*66 + 65)*66 + xx)*256 + tid] = 0;
  }
}

// ---------------- unified weight prep: all repacks + BN fold in ONE launch ----------------
__global__ void prep_k(const float* __restrict__ conv_w, const float* __restrict__ qkv_w,
                       const float* __restrict__ proj_w, const float* __restrict__ fc1_w,
                       const float* __restrict__ fc2_w, const float* __restrict__ conv_b,
                       const float* __restrict__ bn_g, const float* __restrict__ bn_b,
                       const float* __restrict__ bn_m, const float* __restrict__ bn_v,
                       ushort* __restrict__ Wc, ushort* __restrict__ Wq, ushort* __restrict__ Wp,
                       ushort* __restrict__ W1, ushort* __restrict__ W2,
                       float* __restrict__ scv, float* __restrict__ shv)
{
  const long total = 589824L + 393216 + 131072 + 524288 + 524288 + 256;
  for (long idx = (long)blockIdx.x*256 + threadIdx.x; idx < total; idx += (long)gridDim.x*256){
    long e = idx;
    if (e < 589824){
      int co = (int)(e / 2304), kk = (int)(e % 2304);
      int dd = kk >> 8, ci = kk & 255;
      Wc[e] = f2bf(conv_w[((long)(co*256 + ci))*9 + dd]);
      continue;
    }
    e -= 589824;
    if (e < 393216){
      int l = (int)(e / 196608), r = (int)(e % 196608);
      int k = r / 768, n = r % 768;
      Wq[(long)l*196608 + (long)n*256 + k] = f2bf(qkv_w[(long)l*196608 + r]);
      continue;
    }
    e -= 393216;
    if (e < 131072){
      int l = (int)(e / 65536), r = (int)(e % 65536);
      int k = r >> 8, n = r & 255;
      Wp[(long)l*65536 + n*256 + k] = f2bf(proj_w[(long)l*65536 + r]);
      continue;
    }
    e -= 131072;
    if (e < 524288){
      int l = (int)(e / 262144), r = (int)(e % 262144);
      int k = r >> 10, n = r & 1023;
      W1[(long)l*262144 + (long)n*256 + k] = f2bf(fc1_w[(long)l*262144 + r]);
      continue;
    }
    e -= 524288;
    if (e < 524288){
      int l = (int)(e / 262144), r = (int)(e % 262144);
      int k = r >> 8, n = r & 255;
      W2[(long)l*262144 + (long)n*1024 + k] = f2bf(fc2_w[(long)l*262144 + r]);
      continue;
    }
    e -= 524288;
    {
      int n = (int)e;
      float s = bn_g[n] * rsqrtf(bn_v[n] + EPSV);
      scv[n] = s;
      shv[n] = (conv_b[n] - bn_m[n])*s + bn_b[n];
    }
  }
}

// ================= conv GEMM (K=2304): BM=64, BN=256, BK=64 double-buffered + swizzled =================
// fused: t=LN0(v*sc+sh) -> T ; Xb = LN_{g2,b2}(t)
__global__ __launch_bounds__(256) void gemm_conv(
    const ushort* __restrict__ Xin, const ushort* __restrict__ Wt,
    const float* __restrict__ sc, const float* __restrict__ sh,
    float* __restrict__ T, const float* __restrict__ g1, const float* __restrict__ b1,
    const float* __restrict__ g2, const float* __restrict__ b2,
    ushort* __restrict__ Xb)
{
  const int K = 2304;
  __shared__ ushort SMEM[40960];
  const int tid = threadIdx.x, wid = tid>>6, lane = tid&63;
  const int m0 = blockIdx.x*64;
  const int l15 = lane&15, lg = lane>>4;
  const int rS = wid*8 + (lane>>3);
  const int cS = (((lane&7) ^ (lane>>3))*8);

  const ushort* pA[2];
  #pragma unroll
  for (int j=0;j<2;j++){
    int t = m0 + j*32 + rS;
    int b = t>>12, y = (t>>6)&63, x = t&63;
    pA[j] = Xin + ((long)((b*66 + y+1)*66) + (x+1))*256 + cS;
  }
  const ushort* pB[8];
  #pragma unroll
  for (int j=0;j<8;j++) pB[j] = Wt + (long)(j*32 + rS)*K + cS;

  auto stage = [&](int buf, int k0){
    ushort* AsB = SMEM + buf*20480;
    ushort* BsB = AsB + 4096;
    int dd = k0 >> 8;
    int dy = dd/3, dx = dd - dy*3;
    int koffA = ((dy-1)*66 + (dx-1))*256 + (k0 & 255);
    #pragma unroll
    for (int j=0;j<2;j++)
      gload16(pA[j] + koffA, (void*)&AsB[(j*256 + wid*64)*8]);
    #pragma unroll
    for (int j=0;j<8;j++)
      gload16(pB[j] + k0, (void*)&BsB[(j*256 + wid*64)*8]);
  };

  f4v acc[4][4] = {};

  int cur = 0;
  stage(0, 0);
  __syncthreads();
  for (int k0=0; k0<K; k0+=64){
    if (k0 + 64 < K) stage(cur^1, k0 + 64);
    const ushort* AsB = SMEM + cur*20480;
    const ushort* BsB = AsB + 4096;
    #pragma unroll
    for (int kk=0; kk<2; kk++){
      s8v a[4], b[4];
      const int kch = ((kk*4 + lg) ^ (l15 & 7))*8;
      #pragma unroll
      for (int mi=0;mi<4;mi++) a[mi] = *(const s8v*)&AsB[(mi*16 + l15)*64 + kch];
      #pragma unroll
      for (int ni=0;ni<4;ni++) b[ni] = *(const s8v*)&BsB[(wid*64 + ni*16 + l15)*64 + kch];
      #pragma unroll
      for (int mi=0;mi<4;mi++)
        #pragma unroll
        for (int ni=0;ni<4;ni++)
          acc[mi][ni] = __builtin_amdgcn_mfma_f32_16x16x32_bf16(a[mi], b[ni], acc[mi][ni], 0,0,0);
    }
    __syncthreads();
    cur ^= 1;
  }

  float* CT = (float*)SMEM;
  #pragma unroll
  for (int mi=0;mi<4;mi++)
    #pragma unroll
    for (int ni=0;ni<4;ni++)
      #pragma unroll
      for (int r=0;r<4;r++)
        CT[(mi*16 + lg*4 + r)*256 + wid*64 + ni*16 + l15] = acc[mi][ni][r];
  __syncthreads();

  const int c0 = lane*4;
  const float4 scv4 = *(const float4*)&sc[c0], shv4 = *(const float4*)&sh[c0];
  const float4 g1v = *(const float4*)&g1[c0], b1v = *(const float4*)&b1[c0];
  const float4 g2v = *(const float4*)&g2[c0], b2v = *(const float4*)&b2[c0];

  for (int t=0; t<16; t++){
    const int r = wid*16 + t;
    const long gmr = m0 + r;
    float4 v = *(float4*)&CT[r*256 + c0];
    float4 t4;
    t4.x = v.x*scv4.x + shv4.x; t4.y = v.y*scv4.y + shv4.y;
    t4.z = v.z*scv4.z + shv4.z; t4.w = v.w*scv4.w + shv4.w;
    float mu = wsum(t4.x+t4.y+t4.z+t4.w) * (1.0f/256.0f);
    float d0=t4.x-mu, d1=t4.y-mu, d2=t4.z-mu, d3=t4.w-mu;
    float rs = rsqrtf(wsum(d0*d0+d1*d1+d2*d2+d3*d3)*(1.0f/256.0f) + EPSV);
    float u0 = d0*rs*g1v.x + b1v.x, u1 = d1*rs*g1v.y + b1v.y;
    float u2 = d2*rs*g1v.z + b1v.z, u3 = d3*rs*g1v.w + b1v.w;
    float4 u = {u0,u1,u2,u3};
    *(float4*)&T[gmr*256 + c0] = u;
    float mu2 = wsum(u0+u1+u2+u3) * (1.0f/256.0f);
    float e0=u0-mu2, e1=u1-mu2, e2=u2-mu2, e3=u3-mu2;
    float rs2 = rsqrtf(wsum(e0*e0+e1*e1+e2*e2+e3*e3)*(1.0f/256.0f) + EPSV);
    ushort4 o; o.x=f2bf(e0*rs2*g2v.x + b2v.x); o.y=f2bf(e1*rs2*g2v.y + b2v.y);
    o.z=f2bf(e2*rs2*g2v.z + b2v.z); o.w=f2bf(e3*rs2*g2v.w + b2v.w);
    *(ushort4*)&Xb[gmr*256 + c0] = o;
  }
}

// ================= residual GEMM: BM=64, BN=256, BK=32 DOUBLE-buffered (40KB), 2-pass epilogue ====
template<int EPI>
__global__ __launch_bounds__(256) void gemm_res(
    const ushort* __restrict__ A, const ushort* __restrict__ Wt, const float* __restrict__ bias,
    float* __restrict__ T, const float* __restrict__ g1, const float* __restrict__ b1,
    ushort* __restrict__ Xb, float* __restrict__ dout, int K)
{
  __shared__ ushort SMEM[20480];
  const int tid = threadIdx.x, wid = tid>>6, lane = tid&63;
  const int m0 = blockIdx.x*64;
  const int l15 = lane&15, lg = lane>>4;
  const int rowS = wid*16 + (lane>>2);
  const int cSrc = (((lane&3) ^ ((lane>>3)&3))*8);

  const ushort* pA = A + (long)(m0 + rowS)*K + cSrc;
  const ushort* pB[4];
  #pragma unroll
  for (int j=0;j<4;j++) pB[j] = Wt + (long)(j*64 + rowS)*K + cSrc;

  auto stage = [&](int buf, int k0){
    ushort* S = SMEM + buf*10240;
    gload16(pA + k0, (void*)&S[tid*8]);
    #pragma unroll
    for (int j=0;j<4;j++)
      gload16(pB[j] + k0, (void*)&S[2048 + j*2048 + tid*8]);
  };

  f4v acc[4][4] = {};

  int cur = 0;
  stage(0, 0);
  __syncthreads();
  for (int k0=0; k0<K; k0+=32){
    if (k0 + 32 < K) stage(cur^1, k0 + 32);
    const ushort* As_ = SMEM + cur*10240;
    const ushort* Bs_ = As_ + 2048;
    const int kch = (lg ^ ((l15>>1)&3))*8;
    s8v a[4], b[4];
    #pragma unroll
    for (int mi=0;mi<4;mi++) a[mi] = *(const s8v*)&As_[(mi*16 + l15)*32 + kch];
    #pragma unroll
    for (int ni=0;ni<4;ni++) b[ni] = *(const s8v*)&Bs_[(wid*64 + ni*16 + l15)*32 + kch];
    #pragma unroll
    for (int mi=0;mi<4;mi++)
      #pragma unroll
      for (int ni=0;ni<4;ni++)
        acc[mi][ni] = __builtin_amdgcn_mfma_f32_16x16x32_bf16(a[mi], b[ni], acc[mi][ni], 0,0,0);
    __syncthreads();
    cur ^= 1;
  }

  float* CT = (float*)SMEM;
  const int c0 = lane*4;
  const float4 bias4 = *(const float4*)&bias[c0];
  float4 g1v, b1v;
  if (EPI==1){ g1v = *(const float4*)&g1[c0]; b1v = *(const float4*)&b1[c0]; }
  const int b_ = m0>>12, y_ = (m0>>6)&63;

  #pragma unroll
  for (int p=0; p<2; p++){
    #pragma unroll
    for (int mi=2*p; mi<2*p+2; mi++)
      #pragma unroll
      for (int ni=0;ni<4;ni++)
        #pragma unroll
        for (int r=0;r<4;r++)
          CT[((mi-2*p)*16 + lg*4 + r)*256 + wid*64 + ni*16 + l15] = acc[mi][ni][r];
    __syncthreads();
    for (int t=0; t<8; t++){
      const int r = wid*8 + t;
      const long gmr = m0 + p*32 + r;
      float4 v = *(float4*)&CT[r*256 + c0];
      float4 rv = *(float4*)&T[gmr*256 + c0];
      float4 t4;
      t4.x = rv.x + v.x + bias4.x; t4.y = rv.y + v.y + bias4.y;
      t4.z = rv.z + v.z + bias4.z; t4.w = rv.w + v.w + bias4.w;
      if (EPI==3){
        *(float4*)&CT[r*256 + c0] = t4;
      } else {
        *(float4*)&T[gmr*256 + c0] = t4;
        float mu = wsum(t4.x+t4.y+t4.z+t4.w) * (1.0f/256.0f);
        float d0=t4.x-mu, d1=t4.y-mu, d2=t4.z-mu, d3=t4.w-mu;
        float rs = rsqrtf(wsum(d0*d0+d1*d1+d2*d2+d3*d3)*(1.0f/256.0f) + EPSV);
        ushort4 o; o.x=f2bf(d0*rs*g1v.x + b1v.x); o.y=f2bf(d1*rs*g1v.y + b1v.y);
        o.z=f2bf(d2*rs*g1v.z + b1v.z); o.w=f2bf(d3*rs*g1v.w + b1v.w);
        *(ushort4*)&Xb[gmr*256 + c0] = o;
      }
    }
    __syncthreads();
    if (EPI==3){
      float* obase = dout + (long)b_*524288 + (long)y_*64 + p*32;
      for (int it=0; it<32; it++){
        int e = it*256 + tid;
        int c = e>>5, xl = e&31;
        obase[(long)(c>>7)*4194304 + (long)(c&127)*4096 + xl] = CT[xl*256 + c];
      }
      __syncthreads();
    }
  }
}

// ---------------- fc1 GEMM (N=1024): BM=BN=128, BK=32 DOUBLE-buffered (32KB), bias+GELU ----------------
#define BM 128
#define BN 128
__global__ __launch_bounds__(256) void gemm_fc1(
    const ushort* __restrict__ A,
    const ushort* __restrict__ Wt, const float* __restrict__ bias,
    ushort* __restrict__ outb, int N, int K)
{
  __shared__ ushort SMEM[16384];
  const int tid = threadIdx.x, wid = tid>>6, lane = tid&63;
  const int m0 = blockIdx.x*BM, n0 = blockIdx.y*BN;
  const int wm = (wid>>1)*64, wn = (wid&1)*64;
  const int l15 = lane&15, lg = lane>>4;
  const int rowS = wid*16 + (lane>>2);
  const int cSrc = (((lane&3) ^ ((lane>>3)&3))*8);

  const ushort* pA[2];
  #pragma unroll
  for (int j=0;j<2;j++) pA[j] = A + (long)(m0 + j*64 + rowS)*K + cSrc;
  const ushort* pB[2];
  #pragma unroll
  for (int j=0;j<2;j++) pB[j] = Wt + (long)(n0 + j*64 + rowS)*K + cSrc;

  auto stage = [&](int buf, int k0){
    ushort* S = SMEM + buf*8192;
    #pragma unroll
    for (int j=0;j<2;j++)
      gload16(pA[j] + k0, (void*)&S[j*2048 + tid*8]);
    #pragma unroll
    for (int j=0;j<2;j++)
      gload16(pB[j] + k0, (void*)&S[4096 + j*2048 + tid*8]);
  };

  f4v acc[4][4] = {};

  int cur = 0;
  stage(0, 0);
  __syncthreads();
  for (int k0=0; k0<K; k0+=32){
    if (k0 + 32 < K) stage(cur^1, k0 + 32);
    const ushort* As_ = SMEM + cur*8192;
    const ushort* Bs_ = As_ + 4096;
    const int kch = (lg ^ ((l15>>1)&3))*8;
    s8v a[4], b[4];
    #pragma unroll
    for (int mi=0;mi<4;mi++) a[mi] = *(const s8v*)&As_[(wm + mi*16 + l15)*32 + kch];
    #pragma unroll
    for (int ni=0;ni<4;ni++) b[ni] = *(const s8v*)&Bs_[(wn + ni*16 + l15)*32 + kch];
    #pragma unroll
    for (int mi=0;mi<4;mi++)
      #pragma unroll
      for (int ni=0;ni<4;ni++)
        acc[mi][ni] = __builtin_amdgcn_mfma_f32_16x16x32_bf16(a[mi], b[ni], acc[mi][ni], 0,0,0);
    __syncthreads();
    cur ^= 1;
  }

  float* CT = (float*)SMEM;
  #pragma unroll
  for (int p=0; p<2; p++){
    if ((wid>>1) == p){
      #pragma unroll
      for (int mi=0;mi<4;mi++)
        #pragma unroll
        for (int ni=0;ni<4;ni++)
          #pragma unroll
          for (int r=0;r<4;r++)
            CT[(mi*16 + lg*4 + r)*128 + wn + ni*16 + l15] = acc[mi][ni][r];
    }
    __syncthreads();
    #pragma unroll
    for (int it=0; it<8; it++){
      int e = it*256 + tid;
      int row = e >> 5;
      int c4 = e & 31;
      float4 v = *(float4*)&CT[row*128 + c4*4];
      int gm = m0 + p*64 + row;
      int gn = n0 + c4*4;
      float4 bv = *(const float4*)&bias[gn];
      float t0 = gelu_f(v.x + bv.x), t1 = gelu_f(v.y + bv.y);
      float t2 = gelu_f(v.z + bv.z), t3 = gelu_f(v.w + bv.w);
      ushort4 u; u.x=f2bf(t0); u.y=f2bf(t1); u.z=f2bf(t2); u.w=f2bf(t3);
      *(ushort4*)&outb[(long)gm*N + gn] = u;
    }
    __syncthreads();
  }
}

// ---------------- qkv GEMM (N=768): BM=BN=128, BK=32 DOUBLE-buffered (32KB), window-store ----------------
__global__ __launch_bounds__(256) void gemm_qkv(
    const ushort* __restrict__ A,
    const ushort* __restrict__ Wt,
    ushort* __restrict__ outb, int K)
{
  __shared__ ushort SMEM[16384];
  const int tid = threadIdx.x, wid = tid>>6, lane = tid&63;
  const int m0 = blockIdx.x*BM, n0 = blockIdx.y*BN;
  const int wm = (wid>>1)*64, wn = (wid&1)*64;
  const int l15 = lane&15, lg = lane>>4;
  const int rowS = wid*16 + (lane>>2);
  const int cSrc = (((lane&3) ^ ((lane>>3)&3))*8);

  const ushort* pA[2];
  #pragma unroll
  for (int j=0;j<2;j++) pA[j] = A + (long)(m0 + j*64 + rowS)*K + cSrc;
  const ushort* pB[2];
  #pragma unroll
  for (int j=0;j<2;j++) pB[j] = Wt + (long)(n0 + j*64 + rowS)*K + cSrc;

  auto stage = [&](int buf, int k0){
    ushort* S = SMEM + buf*8192;
    #pragma unroll
    for (int j=0;j<2;j++)
      gload16(pA[j] + k0, (void*)&S[j*2048 + tid*8]);
    #pragma unroll
    for (int j=0;j<2;j++)
      gload16(pB[j] + k0, (void*)&S[4096 + j*2048 + tid*8]);
  };

  f4v acc[4][4] = {};

  int cur = 0;
  stage(0, 0);
  __syncthreads();
  for (int k0=0; k0<K; k0+=32){
    if (k0 + 32 < K) stage(cur^1, k0 + 32);
    const ushort* As_ = SMEM + cur*8192;
    const ushort* Bs_ = As_ + 4096;
    const int kch = (lg ^ ((l15>>1)&3))*8;
    s8v a[4], b[4];
    #pragma unroll
    for (int mi=0;mi<4;mi++) a[mi] = *(const s8v*)&As_[(wm + mi*16 + l15)*32 + kch];
    #pragma unroll
    for (int ni=0;ni<4;ni++) b[ni] = *(const s8v*)&Bs_[(wn + ni*16 + l15)*32 + kch];
    #pragma unroll
    for (int mi=0;mi<4;mi++)
      #pragma unroll
      for (int ni=0;ni<4;ni++)
        acc[mi][ni] = __builtin_amdgcn_mfma_f32_16x16x32_bf16(a[mi], b[ni], acc[mi][ni], 0,0,0);
    __syncthreads();
    cur ^= 1;
  }

  ushort* CB = SMEM;
  #pragma unroll
  for (int ni=0;ni<4;ni++){
    const int c = wn + ni*16 + l15;
    const int j = c>>3, ce = c&7;
    #pragma unroll
    for (int mi=0;mi<4;mi++)
      #pragma unroll
      for (int r=0;r<4;r++){
        const int row = wm + mi*16 + lg*4 + r;
        CB[row*128 + (((j ^ (row&7))<<3) | ce)] = f2bf(acc[mi][ni][r]);
      }
  }
  __syncthreads();

  const int tile = n0 >> 8;
  const int brq  = (n0 >> 7) & 1;
  const int b_   = m0 >> 12;
  const int Y0   = (m0 >> 6) & 63;
  if (brq == 0){
    #pragma unroll
    for (int it=0; it<8; it++){
      int g = it*256 + tid;
      int seg = g >> 4, q = g & 15;
      int h = seg >> 5, wv = seg & 31;
      int svi = q >> 2, c8 = q & 3;
      int gm_local = (svi>>1)*64 + wv*2 + (svi&1);
      int jc = h*4 + c8;
      uint4 v = *(uint4*)&CB[gm_local*128 + ((jc ^ (gm_local&7))<<3)];
      long rowb = ((long)(tile*2)*4 + h)*32768L + ((long)b_*32 + wv)*128 + (Y0*2 + svi);
      *(uint4*)&outb[rowb*32 + c8*8] = v;
    }
  } else {
    const int wv = Y0 >> 1;
    #pragma unroll
    for (int it=0; it<8; it++){
      int g = it*256 + tid;
      int h = g >> 9, rem = g & 511, sv = rem >> 2, c8 = rem & 3;
      int jc = h*4 + c8;
      uint4 v = *(uint4*)&CB[sv*128 + ((jc ^ (sv&7))<<3)];
      long rowb = ((long)(tile*2 + 1)*4 + h)*32768L + ((long)b_*32 + wv)*128 + sv;
      *(uint4*)&outb[rowb*32 + c8*8] = v;
    }
  }
}

// ---------------- stripe-window attention + LePE (swapped-QK^T, in-register P) ----------------
__global__ __launch_bounds__(256) void attn_k(
    const ushort* __restrict__ QKVw, ushort* __restrict__ ATT,
    const float* __restrict__ lepe_w, const float* __restrict__ lepe_b, int layer)
{
  __shared__ ushort q_lds[128][36];
  __shared__ ushort k_lds[128][36];
  __shared__ ushort vT[32][132];
  __shared__ float wl[32][9];
  __shared__ float bl[32];
  const int tid = threadIdx.x, wid = tid>>6, lane = tid&63;
  const int b = blockIdx.y;
  const int br = blockIdx.z;
  const int w = blockIdx.x>>2, h = blockIdx.x&3;
  const int choff = br*128 + h*32;
  const int l15 = lane&15, lg = lane>>4;

  const long rowbase = ((long)b*32 + w)*128;
  const ushort* qb = QKVw + (((long)(0*2+br)*4 + h)*32768L + rowbase)*32;
  const ushort* kb = QKVw + (((long)(1*2+br)*4 + h)*32768L + rowbase)*32;
  const ushort* vb = QKVw + (((long)(2*2+br)*4 + h)*32768L + rowbase)*32;

  for (int e = tid; e < 512; e += 256){
    int row = e>>2, c4 = (e&3)*8;
    *(uint4*)&q_lds[row][c4] = *(const uint4*)(qb + (long)e*8);
    *(uint4*)&k_lds[row][c4] = *(const uint4*)(kb + (long)e*8);
    uint4 val = *(const uint4*)(vb + (long)e*8);
    const ushort* u = (const ushort*)&val;
    #pragma unroll
    for (int jj=0;jj<8;jj++) vT[c4+jj][row] = u[jj];
  }
  for (int e = tid; e < 288; e += 256){
    int d = e/9, tap = e%9;
    wl[d][tap] = lepe_w[((long)((layer*2+br)*128 + h*32 + d))*9 + tap];
  }
  if (tid < 32) bl[tid] = lepe_b[(layer*2+br)*128 + h*32 + tid];
  __syncthreads();

  const int wrow = wid*32;
  const float scale = 0.17677669529663689f;
  const int srcE = (lane & 15) | ((lane & 16) << 1);
  const int srcO = srcE + 16;
  const bool hi = (lane >= 32);
  const int HsL = (br==0)?64:2, WsL = (br==0)?2:64;

  #pragma unroll
  for (int mi=0; mi<2; mi++){
    s8v aq = *(const s8v*)&q_lds[wrow + mi*16 + l15][lg*8];
    f4v S[8];
    #pragma unroll
    for (int ni=0; ni<8; ni++){
      s8v bk = *(const s8v*)&k_lds[ni*16 + l15][lg*8];
      f4v z = {0.f,0.f,0.f,0.f};
      S[ni] = __builtin_amdgcn_mfma_f32_16x16x32_bf16(bk, aq, z, 0,0,0);
    }
    float mx = -1e30f;
    #pragma unroll
    for (int ni=0; ni<8; ni++)
      #pragma unroll
      for (int r=0;r<4;r++){ S[ni][r] *= scale; mx = fmaxf(mx, S[ni][r]); }
    mx = fmaxf(mx, __shfl_xor(mx, 16));
    mx = fmaxf(mx, __shfl_xor(mx, 32));
    float sum = 0.f;
    #pragma unroll
    for (int ni=0; ni<8; ni++)
      #pragma unroll
      for (int r=0;r<4;r++){ S[ni][r] = __expf(S[ni][r]-mx); sum += S[ni][r]; }
    sum += __shfl_xor(sum, 16);
    sum += __shfl_xor(sum, 32);
    const float inv = 1.0f / sum;
    unsigned int Alo[8], Ahi[8];
    #pragma unroll
    for (int ni=0; ni<8; ni++){
      Alo[ni] = (unsigned)f2bf(S[ni][0]*inv) | ((unsigned)f2bf(S[ni][1]*inv)<<16);
      Ahi[ni] = (unsigned)f2bf(S[ni][2]*inv) | ((unsigned)f2bf(S[ni][3]*inv)<<16);
    }
    f4v acc2[2] = {{0.f,0.f,0.f,0.f},{0.f,0.f,0.f,0.f}};
    #pragma unroll
    for (int ks=0; ks<4; ks++){
      unsigned e0 = (unsigned)__shfl((int)Alo[2*ks],   srcE);
      unsigned e1 = (unsigned)__shfl((int)Ahi[2*ks],   srcE);
      unsigned e2 = (unsigned)__shfl((int)Alo[2*ks+1], srcE);
      unsigned e3 = (unsigned)__shfl((int)Ahi[2*ks+1], srcE);
      unsigned o0 = (unsigned)__shfl((int)Alo[2*ks],   srcO);
      unsigned o1 = (unsigned)__shfl((int)Ahi[2*ks],   srcO);
      unsigned o2 = (unsigned)__shfl((int)Alo[2*ks+1], srcO);
      unsigned o3 = (unsigned)__shfl((int)Ahi[2*ks+1], srcO);
      union { unsigned u[4]; s8v v; } ap;
      ap.u[0] = hi?e2:e0; ap.u[1] = hi?e3:e1; ap.u[2] = hi?o2:o0; ap.u[3] = hi?o3:o1;
      #pragma unroll
      for (int di=0; di<2; di++){
        s8v bv = *(const s8v*)&vT[di*16 + l15][ks*32 + lg*8];
        acc2[di] = __builtin_amdgcn_mfma_f32_16x16x32_bf16(ap.v, bv, acc2[di], 0,0,0);
      }
    }
    #pragma unroll
    for (int di=0; di<2; di++)
      #pragma unroll
      for (int r=0;r<4;r++){
        int s = wrow + mi*16 + lg*4 + r;
        int d = di*16 + l15;
        float v = acc2[di][r] + bl[d];
        int hs, ws2;
        if (br==0){ hs = s>>1; ws2 = s&1; }
        else      { hs = s>>6; ws2 = s&63; }
        #pragma unroll
        for (int a=-1;a<=1;a++)
          #pragma unroll
          for (int bb=-1;bb<=1;bb++){
            int h2 = hs+a, w2 = ws2+bb;
            if (h2>=0 && h2<HsL && w2>=0 && w2<WsL){
              int s2 = h2*WsL + w2;
              v += wl[d][(a+1)*3 + (bb+1)] * bf2f(vT[d][s2]);
            }
          }
        int y, x;
        if (br==0){ y = s>>1; x = (w<<1)|(s&1); }
        else      { y = (w<<1)|(s>>6); x = s&63; }
        long tok = ((long)b*64 + y)*64 + x;
        ATT[tok*256 + choff + d] = f2bf(v);
      }
  }
}

extern "C" void kernel_launch(void* const* d_in, const int* in_sizes, int n_in,
                              void* d_out, int out_size, void* d_ws, size_t ws_size,
                              hipStream_t stream)
{
  (void)in_sizes; (void)n_in; (void)out_size;
  const float* x1     = (const float*)d_in[0];
  const float* x2     = (const float*)d_in[1];
  const float* conv_w = (const float*)d_in[2];
  const float* conv_b = (const float*)d_in[3];
  const float* bn_g   = (const float*)d_in[4];
  const float* bn_b   = (const float*)d_in[5];
  const float* bn_m   = (const float*)d_in[6];
  const float* bn_v   = (const float*)d_in[7];
  const float* ln0_g  = (const float*)d_in[8];
  const float* ln0_b  = (const float*)d_in[9];
  const float* n1_g   = (const float*)d_in[10];
  const float* n1_b   = (const float*)d_in[11];
  const float* qkv_w  = (const float*)d_in[12];
  const float* lepe_w = (const float*)d_in[13];
  const float* lepe_b = (const float*)d_in[14];
  const float* proj_w = (const float*)d_in[15];
  const float* proj_b = (const float*)d_in[16];
  const float* n2_g   = (const float*)d_in[17];
  const float* n2_b   = (const float*)d_in[18];
  const float* fc1_w  = (const float*)d_in[19];
  const float* fc1_b  = (const float*)d_in[20];
  const float* fc2_w  = (const float*)d_in[21];
  const float* fc2_b  = (const float*)d_in[22];

  if (ws_size < 121767936ULL){
    hipMemsetAsync(d_out, 0, (size_t)out_size*4, stream);
    return;
  }

  // ---- workspace (audited: no in-place read/write, all lifetimes disjoint) ----
  char* ws = (char*)d_ws;
  ushort* Xin  = (ushort*)ws;
  ushort* QKVb = (ushort*)ws;
  ushort* H1b  = (ushort*)ws;
  ushort* ATTb = (ushort*)(ws + 50331648);
  float*  T    = (float*)(ws + 67108864);
  ushort* Xb   = (ushort*)(ws + 100663296);
  size_t off = 117440512;
  ushort* Wc   = (ushort*)(ws + off); off += 1179648;
  ushort* Wq   = (ushort*)(ws + off); off += 786432;
  ushort* Wp   = (ushort*)(ws + off); off += 262144;
  ushort* W1   = (ushort*)(ws + off); off += 1048576;
  ushort* W2   = (ushort*)(ws + off); off += 1048576;
  float*  scv  = (float*)(ws + off);  off += 1024;
  float*  shv  = (float*)(ws + off);  off += 1024;

  repack_in_k<<<dim3(64,8), 256, 0, stream>>>(x1, x2, Xin);
  prep_k<<<1024, 256, 0, stream>>>(conv_w, qkv_w, proj_w, fc1_w, fc2_w,
                                   conv_b, bn_g, bn_b, bn_m, bn_v,
                                   Wc, Wq, Wp, W1, W2, scv, shv);

  // fused conv+BN+LN0+n1(layer0): -> T, Xb
  gemm_conv<<<512,256,0,stream>>>(Xin, Wc, scv, shv, T, ln0_g, ln0_b, n1_g, n1_b, Xb);

  for (int i=0;i<2;i++){
    gemm_qkv<<<dim3(256,6),256,0,stream>>>(Xb, Wq + (long)i*196608, QKVb, 256);
    attn_k<<<dim3(128,8,2),256,0,stream>>>(QKVb, ATTb, lepe_w, lepe_b, i);
    gemm_res<1><<<512,256,0,stream>>>(ATTb, Wp + (long)i*65536, proj_b + i*256,
                                      T, n2_g + i*256, n2_b + i*256, Xb, nullptr, 256);
    gemm_fc1<<<dim3(256,8),256,0,stream>>>(Xb, W1 + (long)i*262144, fc1_b + i*1024, H1b, 1024, 256);
    if (i == 0){
      gemm_res<1><<<512,256,0,stream>>>(H1b, W2, fc2_b,
                                        T, n1_g + 256, n1_b + 256, Xb, nullptr, 1024);
    } else {
      gemm_res<3><<<512,256,0,stream>>>(H1b, W2 + 262144, fc2_b + 256,
                                        T, nullptr, nullptr, nullptr, (float*)d_out, 1024);
    }
  }
}